// Round 4
// baseline (1736.905 us; speedup 1.0000x reference)
//
// GatedTransformerXLLayer — MI355X (gfx950) — round 4:
//   + counted-vmcnt 3-deep pipeline in gemm_k (T4): raw s_barrier, waits
//     vmcnt(LPS) not 0 -> prefetch for K-tiles t+1,t+2 stays in flight
//     (r3: conflicts 0 but MfmaUtil still 24% -> 2-phase barrier drain was
//      the critical path, exactly m233's 72% stall)
//   (T2 swizzle kept; rel-shift split kept)
//
// D=1024 H=16 HD=64 HID=4096 CUR=512 PREV=512 FULL=1024 BS=16

#include <hip/hip_runtime.h>
#include <stdint.h>

typedef _Float16 h16;
typedef __attribute__((ext_vector_type(8))) _Float16 f16x8;
typedef __attribute__((ext_vector_type(4))) _Float16 f16x4;
typedef __attribute__((ext_vector_type(4))) float f32x4;

enum { F_OBF = 1, F_BIAS = 2, F_RELU = 4, F_ACC = 8, F_DUAL = 16, F_SHIFT = 32, F_ACCH = 64 };

static __device__ __forceinline__ void gload16(const void* g, void* l) {
  __builtin_amdgcn_global_load_lds((__attribute__((address_space(1))) void*)g,
                                   (__attribute__((address_space(3))) void*)l,
                                   16, 0, 0);
}

// ---------------------------------------------------------------------------
// Generic MFMA GEMM: C = A(MxK) @ Bt(NxK)^T, fp16 in, f32 accum.
// LDS tile [R][32] fp16, XOR-swizzled via pre-permuted global source (T2).
// 3-deep staging pipeline with counted vmcnt (T4): per K-step
//   { s_waitcnt vmcnt(LPS|0); s_barrier; stage(kt+2); ds_read(kt); MFMA }
// so the two newer stages' global_load_lds stay in flight across barriers.
// ---------------------------------------------------------------------------
template <int BM, int BN, int WAVES_M, int WAVES_N, int FLAGS>
__global__ __launch_bounds__(256) void gemm_k(
    const h16* __restrict__ A, const h16* __restrict__ B,
    void* __restrict__ Cv, void* __restrict__ C2v,
    const float* __restrict__ bias, const float* __restrict__ bias2,
    int K, int lda, int ldb, int ldc,
    long sAb, long sAh, long sBb, long sBh, long sCb, long sCh) {
  constexpr int BK = 32;
  constexpr int WM = BM / WAVES_M, WN = BN / WAVES_N;
  constexpr int MF = WM / 16, NF = WN / 16;
  constexpr int LPS = BM / 64 + BN / 64;  // global_load_lds per thread per stage
  __shared__ h16 Al[3][BM][BK];
  __shared__ h16 Bl[3][BN][BK];

  const int tid = threadIdx.x, lane = tid & 63, wid = tid >> 6;
  const int wm = wid / WAVES_N, wn = wid % WAVES_N;
  const int z = blockIdx.z, zb = z >> 4, zh = z & 15;
  const h16* Ab = A + zb * sAb + zh * sAh + (long)blockIdx.x * BM * lda;
  const h16* Bb = B + zb * sBb + zh * sBh + (long)blockIdx.y * BN * ldb;

  const int srow = lane >> 2;                              // row within 16-row chunk
  const int skc = (((lane & 3) ^ ((lane >> 3) & 3)) * 8);  // pre-swizzled source slot

  auto stage = [&](int buf, int k0) {
#pragma unroll
    for (int t = 0; t < BM / 64; ++t) {
      const int ii = wid + t * 4;
      gload16(Ab + (long)(ii * 16 + srow) * lda + k0 + skc, &Al[buf][ii * 16][0]);
    }
#pragma unroll
    for (int t = 0; t < BN / 64; ++t) {
      const int ii = wid + t * 4;
      gload16(Bb + (long)(ii * 16 + srow) * ldb + k0 + skc, &Bl[buf][ii * 16][0]);
    }
  };

  f32x4 acc[MF][NF] = {};
  const int nk = K / BK;
  const int ar = lane & 15, ls = lane >> 4;  // fragment row, logical K-slot

  stage(0, 0);
  if (nk > 1) stage(1, BK);
  for (int kt = 0; kt < nk; ++kt) {
    // wait for stage kt only (own loads); newer stages remain in flight
    if (kt == nk - 1) {
      asm volatile("s_waitcnt vmcnt(0)" ::: "memory");
    } else if constexpr (LPS == 4) {
      asm volatile("s_waitcnt vmcnt(4)" ::: "memory");
    } else if constexpr (LPS == 3) {
      asm volatile("s_waitcnt vmcnt(3)" ::: "memory");
    } else {
      asm volatile("s_waitcnt vmcnt(0)" ::: "memory");
    }
    __builtin_amdgcn_s_barrier();
    asm volatile("" ::: "memory");  // keep ds_read/stage below the barrier
    if (kt + 2 < nk) stage((kt + 2) % 3, (kt + 2) * BK);
    const int cur = kt % 3;
    f16x8 af[MF], bv[NF];
#pragma unroll
    for (int m = 0; m < MF; ++m) {
      const int R = wm * WM + m * 16 + ar;
      af[m] = *(const f16x8*)&Al[cur][R][(ls ^ ((R >> 1) & 3)) * 8];
    }
#pragma unroll
    for (int n = 0; n < NF; ++n) {
      const int R = wn * WN + n * 16 + ar;
      bv[n] = *(const f16x8*)&Bl[cur][R][(ls ^ ((R >> 1) & 3)) * 8];
    }
#pragma unroll
    for (int m = 0; m < MF; ++m)
#pragma unroll
      for (int n = 0; n < NF; ++n)
        acc[m][n] = __builtin_amdgcn_mfma_f32_16x16x32_f16(af[m], bv[n], acc[m][n], 0, 0, 0);
  }

  // epilogue: D row = (lane>>4)*4 + r (+16*m), col = lane&15 (+16*n)
  const long coff = (long)zb * sCb + (long)zh * sCh;
#pragma unroll
  for (int m = 0; m < MF; ++m) {
#pragma unroll
    for (int n = 0; n < NF; ++n) {
      const int col = blockIdx.y * BN + wn * WN + n * 16 + ar;
      float bv1 = 0.f, bv2 = 0.f;
      if (FLAGS & F_BIAS) bv1 = bias[col];
      if (FLAGS & F_DUAL) bv2 = bias2[col];
#pragma unroll
      for (int r = 0; r < 4; ++r) {
        const int row = blockIdx.x * BM + wm * WM + m * 16 + (lane >> 4) * 4 + r;
        float val = acc[m][n][r] + bv1;
        if (FLAGS & F_RELU) val = fmaxf(val, 0.f);
        if constexpr ((FLAGS & F_SHIFT) != 0) {
          // rel_shift: S[row][col + row - 511] = val (pure write; covers the
          // whole unmasked region exactly once, masked region left stale)
          const int j = col + row - 511;
          if (j >= 0) ((h16*)Cv)[coff + (long)row * ldc + j] = (h16)val;
        } else if constexpr ((FLAGS & F_ACCH) != 0) {
          h16* p = (h16*)Cv + coff + (long)row * ldc + col;
          *p = (h16)((float)*p + val);
        } else if constexpr ((FLAGS & F_ACC) != 0) {
          float* p = (float*)Cv + coff + (long)row * ldc + col;
          *p = *p + val;
        } else if constexpr ((FLAGS & F_OBF) != 0) {
          ((h16*)Cv)[coff + (long)row * ldc + col] = (h16)val;
          if constexpr ((FLAGS & F_DUAL) != 0)
            ((h16*)C2v)[coff + (long)row * ldc + col] = (h16)(acc[m][n][r] + bv2);
        } else {
          ((float*)Cv)[coff + (long)row * ldc + col] = val;
        }
      }
    }
  }
}

// ---------------------------------------------------------------------------
// Weight transpose: in f32 (K,N) -> out fp16 (N,K)
// ---------------------------------------------------------------------------
__global__ __launch_bounds__(256) void wtrans_k(const float* __restrict__ in,
                                                h16* __restrict__ out, int K, int N) {
  __shared__ float t[32][33];
  const int tx = threadIdx.x & 31, ty = threadIdx.x >> 5;
  const int n0 = blockIdx.x * 32, k0 = blockIdx.y * 32;
#pragma unroll
  for (int j = 0; j < 32; j += 8)
    t[ty + j][tx] = in[(long)(k0 + ty + j) * N + n0 + tx];
  __syncthreads();
#pragma unroll
  for (int j = 0; j < 32; j += 8)
    out[(long)(n0 + ty + j) * K + k0 + tx] = (h16)t[tx][ty + j];
}

__global__ __launch_bounds__(256) void cast_k(const float* __restrict__ in,
                                              h16* __restrict__ out, long n4) {
  const long i = (long)blockIdx.x * 256 + threadIdx.x;
  if (i >= n4) return;
  const float4 v = ((const float4*)in)[i];
  f16x4 o;
  o[0] = (h16)v.x; o[1] = (h16)v.y; o[2] = (h16)v.z; o[3] = (h16)v.w;
  ((f16x4*)out)[i] = o;
}

__global__ void addbias_k(const float* __restrict__ bq, const float* __restrict__ u,
                          const float* __restrict__ v, float* __restrict__ qu,
                          float* __restrict__ qv) {
  const int c = blockIdx.x * 256 + threadIdx.x;
  if (c < 1024) { qu[c] = bq[c] + u[c]; qv[c] = bq[c] + v[c]; }
}

__global__ __launch_bounds__(256) void zero_out_k(float* __restrict__ out, long n) {
  const long i = (long)blockIdx.x * 256 + threadIdx.x;
  if (i < n) out[i] = 0.f;
}

// LayerNorm over last dim (1024); rows < rows0 from src0, rest from src1.
__global__ __launch_bounds__(256) void ln_k(const float* __restrict__ src0,
                                            const float* __restrict__ src1, int rows0,
                                            const float* __restrict__ g,
                                            const float* __restrict__ b,
                                            h16* __restrict__ out) {
  const int row = blockIdx.x, tid = threadIdx.x;
  const float* src = (row < rows0) ? (src0 + (long)row * 1024)
                                   : (src1 + (long)(row - rows0) * 1024);
  const float4 x = ((const float4*)src)[tid];
  float s = x.x + x.y + x.z + x.w;
  float sq = x.x * x.x + x.y * x.y + x.z * x.z + x.w * x.w;
#pragma unroll
  for (int o = 32; o > 0; o >>= 1) { s += __shfl_down(s, o); sq += __shfl_down(sq, o); }
  __shared__ float red[8];
  const int lane = tid & 63, w = tid >> 6;
  if (lane == 0) { red[w] = s; red[4 + w] = sq; }
  __syncthreads();
  s = red[0] + red[1] + red[2] + red[3];
  sq = red[4] + red[5] + red[6] + red[7];
  const float mu = s * (1.f / 1024.f);
  const float inv = rsqrtf(sq * (1.f / 1024.f) - mu * mu + 1e-5f);
  const float4 gg = ((const float4*)g)[tid], bb = ((const float4*)b)[tid];
  f16x4 o;
  o[0] = (h16)((x.x - mu) * inv * gg.x + bb.x);
  o[1] = (h16)((x.y - mu) * inv * gg.y + bb.y);
  o[2] = (h16)((x.z - mu) * inv * gg.z + bb.z);
  o[3] = (h16)((x.w - mu) * inv * gg.w + bb.w);
  ((f16x4*)(out + (long)row * 1024))[tid] = o;
}

// value: kv[(j*16+b)*2048 + 1024 + h*64 + d] -> vT[(z*64+d)*1024 + j], z=b*16+h
__global__ __launch_bounds__(256) void vtrans_k(const h16* __restrict__ kv,
                                                h16* __restrict__ vT) {
  const int z = blockIdx.y, b = z >> 4, h = z & 15;
  const int j0 = blockIdx.x * 64;
  __shared__ h16 t[64][72];
  const int jj = threadIdx.x >> 3, c = threadIdx.x & 7;
#pragma unroll
  for (int half = 0; half < 2; ++half) {
    const int j = jj + half * 32;
    const f16x8 v = *(const f16x8*)(kv + ((long)(j0 + j) * 16 + b) * 2048 + 1024 + h * 64 + c * 8);
    *(f16x8*)&t[j][c * 8] = v;
  }
  __syncthreads();
#pragma unroll
  for (int half = 0; half < 2; ++half) {
    const int d = jj + half * 32;
    f16x8 o;
#pragma unroll
    for (int k = 0; k < 8; ++k) o[k] = t[c * 8 + k][d];
    *(f16x8*)(vT + ((long)z * 64 + d) * 1024 + j0 + c * 8) = o;
  }
}

// masked softmax in place over rows of S (fp16, row length 1024); row i allows
// j <= i+512; masked tail written as 0 so PV is a plain GEMM.
__global__ __launch_bounds__(256) void softmax_k(h16* __restrict__ S) {
  const long blk = blockIdx.x;
  const int i = (int)(blk & 511);
  h16* row = S + blk * 1024;
  const int tid = threadIdx.x;
  const int jmax = i + 512;
  f16x4 v = *(f16x4*)&row[tid * 4];
  float sv[4];
  float m = -1e30f;
#pragma unroll
  for (int k = 0; k < 4; ++k) {
    const int j = tid * 4 + k;
    sv[k] = (j <= jmax) ? (float)v[k] * 0.125f : -1e30f;
    m = fmaxf(m, sv[k]);
  }
  __shared__ float red[8];
  const int lane = tid & 63, w = tid >> 6;
#pragma unroll
  for (int o = 32; o > 0; o >>= 1) m = fmaxf(m, __shfl_down(m, o));
  if (lane == 0) red[w] = m;
  __syncthreads();
  m = fmaxf(fmaxf(red[0], red[1]), fmaxf(red[2], red[3]));
  float e[4], s = 0.f;
#pragma unroll
  for (int k = 0; k < 4; ++k) {
    e[k] = (sv[k] > -1e29f) ? __expf(sv[k] - m) : 0.f;
    s += e[k];
  }
#pragma unroll
  for (int o = 32; o > 0; o >>= 1) s += __shfl_down(s, o);
  if (lane == 0) red[4 + w] = s;
  __syncthreads();
  s = red[4] + red[5] + red[6] + red[7];
  const float inv = 1.f / s;
#pragma unroll
  for (int k = 0; k < 4; ++k) v[k] = (h16)(e[k] * inv);
  *(f16x4*)&row[tid * 4] = v;
}

// rx = fp16(sigmoid(T[:,0:1024]) * x); T row stride 3072
__global__ __launch_bounds__(256) void gru_rx_k(const float* __restrict__ T,
                                                const float* __restrict__ x,
                                                h16* __restrict__ rx) {
  const long i = (long)blockIdx.x * 256 + threadIdx.x;  // over 2M float4s
  const long row = i >> 8;
  const int c4 = (int)(i & 255);
  const float4 t = *((const float4*)(T + row * 3072) + c4);
  const float4 xx = ((const float4*)x)[i];
  f16x4 o;
  o[0] = (h16)(xx.x / (1.f + __expf(-t.x)));
  o[1] = (h16)(xx.y / (1.f + __expf(-t.y)));
  o[2] = (h16)(xx.z / (1.f + __expf(-t.z)));
  o[3] = (h16)(xx.w / (1.f + __expf(-t.w)));
  ((f16x4*)rx)[i] = o;
}

// o = (1-z)*x + z*tanh(Tg), z = sigmoid(Tz - bg); Tz = T[:,1024:2048], Tg = T[:,2048:3072]
__global__ __launch_bounds__(256) void gru_out_k(const float* __restrict__ T,
                                                 const float* __restrict__ x,
                                                 const float* __restrict__ bg,
                                                 float* __restrict__ outf,
                                                 h16* __restrict__ outh) {
  const long i = (long)blockIdx.x * 256 + threadIdx.x;
  const long row = i >> 8;
  const int c4 = (int)(i & 255);
  const float4 tz = *((const float4*)(T + row * 3072 + 1024) + c4);
  const float4 th = *((const float4*)(T + row * 3072 + 2048) + c4);
  const float4 xx = ((const float4*)x)[i];
  const float4 bb = ((const float4*)bg)[c4];
  float4 o;
  {
    const float z0 = 1.f / (1.f + __expf(-(tz.x - bb.x)));
    const float z1 = 1.f / (1.f + __expf(-(tz.y - bb.y)));
    const float z2 = 1.f / (1.f + __expf(-(tz.z - bb.z)));
    const float z3 = 1.f / (1.f + __expf(-(tz.w - bb.w)));
    o.x = (1.f - z0) * xx.x + z0 * tanhf(th.x);
    o.y = (1.f - z1) * xx.y + z1 * tanhf(th.y);
    o.z = (1.f - z2) * xx.z + z2 * tanhf(th.z);
    o.w = (1.f - z3) * xx.w + z3 * tanhf(th.w);
  }
  ((float4*)outf)[i] = o;
  if (outh != nullptr) {
    f16x4 oh;
    oh[0] = (h16)o.x; oh[1] = (h16)o.y; oh[2] = (h16)o.z; oh[3] = (h16)o.w;
    ((f16x4*)outh)[i] = oh;
  }
}

// ---------------------------------------------------------------------------
extern "C" void kernel_launch(void* const* d_in, const int* in_sizes, int n_in,
                              void* d_out, int out_size, void* d_ws, size_t ws_size,
                              hipStream_t stream) {
  const float* inputs = (const float*)d_in[0];   // (512,16,1024)
  const float* pos    = (const float*)d_in[1];   // (1024,1,1024)
  const float* u      = (const float*)d_in[2];   // (16,64)
  const float* v      = (const float*)d_in[3];
  const float* memory = (const float*)d_in[4];   // (512,16,1024)
  // d_in[5] = mask (recomputed analytically)
  const float* Wkv = (const float*)d_in[6];  const float* bkv = (const float*)d_in[7];
  const float* Wq  = (const float*)d_in[8];  const float* bq  = (const float*)d_in[9];
  const float* Wo  = (const float*)d_in[10]; const float* bo  = (const float*)d_in[11];
  const float* Wp  = (const float*)d_in[12]; const float* bp  = (const float*)d_in[13];
  const float* ln1_g = (const float*)d_in[14]; const float* ln1_b = (const float*)d_in[15];
  const float* ln2_g = (const float*)d_in[16]; const float* ln2_b = (const float*)d_in[17];
  const float* W1 = (const float*)d_in[18]; const float* b1 = (const float*)d_in[19];
  const float* W2 = (const float*)d_in[20]; const float* b2 = (const float*)d_in[21];
  const float* g1_W = (const float*)d_in[22]; const float* g1_U = (const float*)d_in[23];
  const float* g1_bg = (const float*)d_in[24];
  const float* g2_W = (const float*)d_in[25]; const float* g2_U = (const float*)d_in[26];
  const float* g2_bg = (const float*)d_in[27];
  (void)in_sizes; (void)n_in;

  const size_t MB = 1u << 20;
  const size_t NEEDED = 247 * MB;
  const dim3 blk(256);
  if (ws_size < NEEDED) {
    // diagnostic fallback: clean absmax failure instead of a memory fault
    zero_out_k<<<(out_size + 255) / 256, blk, 0, stream>>>((float*)d_out, out_size);
    return;
  }

  char* w = (char*)d_ws;
  // --- static plan (byte offsets, MB units). Liveness-based region reuse. ---
  h16* WoT   = (h16*)(w + 0 * MB);     // 2  MB  [P0..Wo]
  h16* W1T   = (h16*)(w + 2 * MB);     // 8  MB
  h16* W2T   = (h16*)(w + 10 * MB);    // 8  MB
  h16* g1Wb  = (h16*)(w + 18 * MB);    // 6  MB
  h16* g1Ub  = (h16*)(w + 24 * MB);    // 6  MB
  h16* g2Wb  = (h16*)(w + 30 * MB);    // 6  MB
  h16* g2Ub  = (h16*)(w + 36 * MB);    // 6  MB
  h16* WkvT  = (h16*)(w + 42 * MB);    // 4  MB
  h16* WqT   = (h16*)(w + 46 * MB);    // 2  MB
  h16* WpT   = (h16*)(w + 48 * MB);    // 2  MB
  h16* posb  = (h16*)(w + 50 * MB);    // 2  MB
  float* bias_qu = (float*)(w + 52 * MB);          // 4 KB
  float* bias_qv = (float*)(w + 52 * MB + 8192);   // 4 KB
  h16* xb    = (h16*)(w + 53 * MB);    // 16 MB  inputs as fp16
  h16* x1    = (h16*)(w + 69 * MB);    // 32 MB  ln1 out -> vT -> x2|m2, rx2
  char* Rbig =        w + 101 * MB;    // 96 MB  kvb(64)+S(32) -> Tall(f32) -> h1
  h16* qu    = (h16*)(w + 197 * MB);   // 16 MB  -> a1 -> o1f(lo)
  h16* qv    = (h16*)(w + 213 * MB);   // 16 MB  -> rx1 -> o1f(hi)
  h16* rb    = (h16*)(w + 229 * MB);   // 2  MB
  h16* attn  = (h16*)(w + 231 * MB);   // 16 MB  -> o1b
  // total: 247 MB

  h16*   kvb  = (h16*)Rbig;                   // 64 MB (key|value interleaved)
  h16*   S    = (h16*)(Rbig + 64 * MB);       // 32 MB (2-batch attn groups)
  float* Tall = (float*)Rbig;                 // 96 MB GRU pre-activations
  h16*   h1   = (h16*)Rbig;                   // 67 MB MLP hidden
  h16*   vT   = x1;                           // 32 MB (x1 dead after q GEMM)
  h16*   a1   = qu;
  h16*   rx1  = qv;
  float* o1f  = (float*)qu;                   // 32 MB spans qu+qv (both dead)
  h16*   o1b  = attn;                         // attn dead after Wo GEMM
  h16*   x2   = x1;                           // first 16 MB (vT dead post-attn)
  h16*   m2   = x1 + 8L * 1024 * 1024;        // second 16 MB
  h16*   rx2  = x1;                           // x2 slot, dead after W1 GEMM

  // ---- weight prep ----
  wtrans_k<<<dim3(64, 32), blk, 0, stream>>>(Wkv, WkvT, 1024, 2048);
  wtrans_k<<<dim3(32, 32), blk, 0, stream>>>(Wq, WqT, 1024, 1024);
  wtrans_k<<<dim3(32, 32), blk, 0, stream>>>(Wo, WoT, 1024, 1024);
  wtrans_k<<<dim3(32, 32), blk, 0, stream>>>(Wp, WpT, 1024, 1024);
  wtrans_k<<<dim3(128, 32), blk, 0, stream>>>(W1, W1T, 1024, 4096);
  wtrans_k<<<dim3(32, 128), blk, 0, stream>>>(W2, W2T, 4096, 1024);
  cast_k<<<3072, blk, 0, stream>>>(g1_W, g1Wb, 786432);  // y@W.T: already (N,K)
  cast_k<<<3072, blk, 0, stream>>>(g1_U, g1Ub, 786432);
  cast_k<<<3072, blk, 0, stream>>>(g2_W, g2Wb, 786432);
  cast_k<<<3072, blk, 0, stream>>>(g2_U, g2Ub, 786432);
  cast_k<<<1024, blk, 0, stream>>>(pos, posb, 262144);
  cast_k<<<8192, blk, 0, stream>>>(inputs, xb, 2097152);
  addbias_k<<<4, blk, 0, stream>>>(bq, u, v, bias_qu, bias_qv);

  // ---- ln1 over concat(memory, inputs) ----
  ln_k<<<16384, blk, 0, stream>>>(memory, inputs, 8192, ln1_g, ln1_b, x1);

  // ---- projections ----
  gemm_k<128, 128, 2, 2, F_OBF | F_BIAS><<<dim3(128, 16, 1), blk, 0, stream>>>(
      x1, WkvT, kvb, nullptr, bkv, nullptr, 1024, 1024, 1024, 2048, 0, 0, 0, 0, 0, 0);
  gemm_k<128, 128, 2, 2, F_OBF | F_BIAS | F_DUAL><<<dim3(64, 8, 1), blk, 0, stream>>>(
      x1 + 8192L * 1024, WqT, qu, qv, bias_qu, bias_qv, 1024, 1024, 1024, 1024, 0, 0, 0, 0, 0, 0);
  gemm_k<128, 128, 2, 2, F_OBF | F_BIAS><<<dim3(8, 8, 1), blk, 0, stream>>>(
      posb, WpT, rb, nullptr, bp, nullptr, 1024, 1024, 1024, 1024, 0, 0, 0, 0, 0, 0);
  vtrans_k<<<dim3(16, 256), blk, 0, stream>>>(kvb, vT);  // after q GEMM (x1 dead)

  // ---- attention, 8 groups of 2 batches (z local = b_local*16 + h) ----
  for (int g = 0; g < 8; ++g) {
    // position: (q+v) @ r^T, written at rel-shifted columns (covers unmasked region)
    gemm_k<128, 128, 2, 2, F_SHIFT><<<dim3(4, 8, 32), blk, 0, stream>>>(
        qv + (long)g * 2 * 1024, rb, S, nullptr, nullptr, nullptr,
        64, 16384, 1024, 1024,
        1024, 64, 0, 64, 8388608, 524288);
    // content: (q+u) @ key^T, coalesced h16 add into S
    gemm_k<128, 128, 2, 2, F_ACCH><<<dim3(4, 8, 32), blk, 0, stream>>>(
        qu + (long)g * 2 * 1024, kvb + (long)g * 2 * 2048, S, nullptr, nullptr, nullptr,
        64, 16384, 32768, 1024,
        1024, 64, 2048, 64, 8388608, 524288);
    softmax_k<<<16384, blk, 0, stream>>>(S);
    // PV: p @ vT^T -> attn (cur,bs,H*HD)
    gemm_k<128, 64, 4, 1, F_OBF><<<dim3(4, 1, 32), blk, 0, stream>>>(
        S, vT + (long)g * 2097152, attn + (long)g * 2 * 1024, nullptr, nullptr, nullptr,
        1024, 1024, 1024, 16384,
        8388608, 524288, 1048576, 65536, 1024, 64);
  }

  // ---- output projection + relu -> a1 ----
  gemm_k<128, 128, 2, 2, F_OBF | F_BIAS | F_RELU><<<dim3(64, 8, 1), blk, 0, stream>>>(
      attn, WoT, a1, nullptr, bo, nullptr, 1024, 1024, 1024, 1024, 0, 0, 0, 0, 0, 0);

  // ---- GRU gate 1: x = inputs, y = a1 ----
  gemm_k<128, 128, 2, 2, 0><<<dim3(64, 24, 1), blk, 0, stream>>>(
      a1, g1Wb, Tall, nullptr, nullptr, nullptr, 1024, 1024, 1024, 3072, 0, 0, 0, 0, 0, 0);
  gemm_k<128, 128, 2, 2, F_ACC><<<dim3(64, 16, 1), blk, 0, stream>>>(
      xb, g1Ub, Tall, nullptr, nullptr, nullptr, 1024, 1024, 1024, 3072, 0, 0, 0, 0, 0, 0);
  gru_rx_k<<<8192, blk, 0, stream>>>(Tall, inputs, rx1);
  gemm_k<128, 128, 2, 2, F_ACC><<<dim3(64, 8, 1), blk, 0, stream>>>(
      rx1, g1Ub + 2L * 1024 * 1024, Tall + 2048, nullptr, nullptr, nullptr,
      1024, 1024, 1024, 3072, 0, 0, 0, 0, 0, 0);
  gru_out_k<<<8192, blk, 0, stream>>>(Tall, inputs, g1_bg, o1f, o1b);

  // ---- ln2 + MLP ----
  ln_k<<<8192, blk, 0, stream>>>(o1f, o1f, 8192, ln2_g, ln2_b, x2);
  gemm_k<128, 128, 2, 2, F_OBF | F_BIAS | F_RELU><<<dim3(64, 32, 1), blk, 0, stream>>>(
      x2, W1T, h1, nullptr, b1, nullptr, 1024, 1024, 1024, 4096, 0, 0, 0, 0, 0, 0);
  gemm_k<128, 128, 2, 2, F_OBF | F_BIAS | F_RELU><<<dim3(64, 8, 1), blk, 0, stream>>>(
      h1, W2T, m2, nullptr, b2, nullptr, 4096, 4096, 4096, 1024, 0, 0, 0, 0, 0, 0);

  // ---- GRU gate 2: x = o1, y = m2 -> d_out ----
  gemm_k<128, 128, 2, 2, 0><<<dim3(64, 24, 1), blk, 0, stream>>>(
      m2, g2Wb, Tall, nullptr, nullptr, nullptr, 1024, 1024, 1024, 3072, 0, 0, 0, 0, 0, 0);
  gemm_k<128, 128, 2, 2, F_ACC><<<dim3(64, 16, 1), blk, 0, stream>>>(
      o1b, g2Ub, Tall, nullptr, nullptr, nullptr, 1024, 1024, 1024, 3072, 0, 0, 0, 0, 0, 0);
  gru_rx_k<<<8192, blk, 0, stream>>>(Tall, o1f, rx2);
  gemm_k<128, 128, 2, 2, F_ACC><<<dim3(64, 8, 1), blk, 0, stream>>>(
      rx2, g2Ub + 2L * 1024 * 1024, Tall + 2048, nullptr, nullptr, nullptr,
      1024, 1024, 1024, 3072, 0, 0, 0, 0, 0, 0);
  gru_out_k<<<8192, blk, 0, stream>>>(Tall, o1f, g2_bg, (float*)d_out, nullptr);
}

// Round 5
// 1289.828 us; speedup vs baseline: 1.3466x; 1.3466x over previous
//
// GatedTransformerXLLayer — MI355X (gfx950) — round 5:
//   + fused attention kernel (content QK^T + rel-pos band + online softmax +
//     PV) — replaces 40 launches / ~1.5 GB of S traffic. r3/r4 showed the
//     batched K=64 GEMMs were latency/launch-bound, not fixable in-kernel.
//   gemm_k unchanged from r4 (T2 swizzle + 3-buf counted vmcnt).
//
// D=1024 H=16 HD=64 HID=4096 CUR=512 PREV=512 FULL=1024 BS=16

#include <hip/hip_runtime.h>
#include <stdint.h>

typedef _Float16 h16;
typedef __attribute__((ext_vector_type(8))) _Float16 f16x8;
typedef __attribute__((ext_vector_type(4))) _Float16 f16x4;
typedef __attribute__((ext_vector_type(4))) float f32x4;

enum { F_OBF = 1, F_BIAS = 2, F_RELU = 4, F_ACC = 8, F_DUAL = 16 };

static __device__ __forceinline__ void gload16(const void* g, void* l) {
  __builtin_amdgcn_global_load_lds((__attribute__((address_space(1))) void*)g,
                                   (__attribute__((address_space(3))) void*)l,
                                   16, 0, 0);
}

// ---------------------------------------------------------------------------
// Generic MFMA GEMM: C = A(MxK) @ Bt(NxK)^T, fp16 in, f32 accum. (r4 version)
// ---------------------------------------------------------------------------
template <int BM, int BN, int WAVES_M, int WAVES_N, int FLAGS>
__global__ __launch_bounds__(256) void gemm_k(
    const h16* __restrict__ A, const h16* __restrict__ B,
    void* __restrict__ Cv, void* __restrict__ C2v,
    const float* __restrict__ bias, const float* __restrict__ bias2,
    int K, int lda, int ldb, int ldc,
    long sAb, long sAh, long sBb, long sBh, long sCb, long sCh) {
  constexpr int BK = 32;
  constexpr int WM = BM / WAVES_M, WN = BN / WAVES_N;
  constexpr int MF = WM / 16, NF = WN / 16;
  constexpr int LPS = BM / 64 + BN / 64;
  __shared__ h16 Al[3][BM][BK];
  __shared__ h16 Bl[3][BN][BK];

  const int tid = threadIdx.x, lane = tid & 63, wid = tid >> 6;
  const int wm = wid / WAVES_N, wn = wid % WAVES_N;
  const int z = blockIdx.z, zb = z >> 4, zh = z & 15;
  const h16* Ab = A + zb * sAb + zh * sAh + (long)blockIdx.x * BM * lda;
  const h16* Bb = B + zb * sBb + zh * sBh + (long)blockIdx.y * BN * ldb;

  const int srow = lane >> 2;
  const int skc = (((lane & 3) ^ ((lane >> 3) & 3)) * 8);

  auto stage = [&](int buf, int k0) {
#pragma unroll
    for (int t = 0; t < BM / 64; ++t) {
      const int ii = wid + t * 4;
      gload16(Ab + (long)(ii * 16 + srow) * lda + k0 + skc, &Al[buf][ii * 16][0]);
    }
#pragma unroll
    for (int t = 0; t < BN / 64; ++t) {
      const int ii = wid + t * 4;
      gload16(Bb + (long)(ii * 16 + srow) * ldb + k0 + skc, &Bl[buf][ii * 16][0]);
    }
  };

  f32x4 acc[MF][NF] = {};
  const int nk = K / BK;
  const int ar = lane & 15, ls = lane >> 4;

  stage(0, 0);
  if (nk > 1) stage(1, BK);
  for (int kt = 0; kt < nk; ++kt) {
    if (kt == nk - 1) {
      asm volatile("s_waitcnt vmcnt(0)" ::: "memory");
    } else if constexpr (LPS == 4) {
      asm volatile("s_waitcnt vmcnt(4)" ::: "memory");
    } else if constexpr (LPS == 3) {
      asm volatile("s_waitcnt vmcnt(3)" ::: "memory");
    } else {
      asm volatile("s_waitcnt vmcnt(0)" ::: "memory");
    }
    __builtin_amdgcn_s_barrier();
    asm volatile("" ::: "memory");
    if (kt + 2 < nk) stage((kt + 2) % 3, (kt + 2) * BK);
    const int cur = kt % 3;
    f16x8 af[MF], bv[NF];
#pragma unroll
    for (int m = 0; m < MF; ++m) {
      const int R = wm * WM + m * 16 + ar;
      af[m] = *(const f16x8*)&Al[cur][R][(ls ^ ((R >> 1) & 3)) * 8];
    }
#pragma unroll
    for (int n = 0; n < NF; ++n) {
      const int R = wn * WN + n * 16 + ar;
      bv[n] = *(const f16x8*)&Bl[cur][R][(ls ^ ((R >> 1) & 3)) * 8];
    }
#pragma unroll
    for (int m = 0; m < MF; ++m)
#pragma unroll
      for (int n = 0; n < NF; ++n)
        acc[m][n] = __builtin_amdgcn_mfma_f32_16x16x32_f16(af[m], bv[n], acc[m][n], 0, 0, 0);
  }

  const long coff = (long)zb * sCb + (long)zh * sCh;
#pragma unroll
  for (int m = 0; m < MF; ++m) {
#pragma unroll
    for (int n = 0; n < NF; ++n) {
      const int col = blockIdx.y * BN + wn * WN + n * 16 + ar;
      float bv1 = 0.f, bv2 = 0.f;
      if (FLAGS & F_BIAS) bv1 = bias[col];
      if (FLAGS & F_DUAL) bv2 = bias2[col];
#pragma unroll
      for (int r = 0; r < 4; ++r) {
        const int row = blockIdx.x * BM + wm * WM + m * 16 + (lane >> 4) * 4 + r;
        float val = acc[m][n][r] + bv1;
        if (FLAGS & F_RELU) val = fmaxf(val, 0.f);
        if constexpr ((FLAGS & F_ACC) != 0) {
          float* p = (float*)Cv + coff + (long)row * ldc + col;
          *p = *p + val;
        } else if constexpr ((FLAGS & F_OBF) != 0) {
          ((h16*)Cv)[coff + (long)row * ldc + col] = (h16)val;
          if constexpr ((FLAGS & F_DUAL) != 0)
            ((h16*)C2v)[coff + (long)row * ldc + col] = (h16)(acc[m][n][r] + bv2);
        } else {
          ((float*)Cv)[coff + (long)row * ldc + col] = val;
        }
      }
    }
  }
}

// ---------------------------------------------------------------------------
// Fused Transformer-XL attention: per block (z = b*16+h, 64-row i-tile).
// S[i][j] = (q_i+u)·k_j + (q_i+v)·r_{j-i+511}, mask j<=i+512, softmax, @V.
// Position term computed on a 192-wide jj-band per 128-col j-tile:
//   jjb = j0 - i0 + 448;  band idx = jloc - (i - i0) + 63  (in [0,190]).
// K/V staged in LDS (XOR-swizzled); R read direct from global (2 MB, L2-hot).
// ---------------------------------------------------------------------------
__global__ __launch_bounds__(256) void fattn_k(
    const h16* __restrict__ qu, const h16* __restrict__ qv,
    const h16* __restrict__ kvb, const h16* __restrict__ vT,
    const h16* __restrict__ rb, h16* __restrict__ attn) {
  __shared__ h16 Kl[128][64];      // [j][d]   phys slot = (d>>3) ^ (j&7)
  __shared__ h16 Vl[64][128];      // [d][j]   phys slot = (j>>3) ^ (d&7)
  __shared__ h16 Pband[64][200];   // [row][band] (192 used, pad vs conflicts)
  __shared__ h16 Plds[4][16][128]; // per-wave P in A-layout, slot^(row&7)

  const int tid = threadIdx.x, lane = tid & 63, wv = tid >> 6;
  const int z = blockIdx.x, b = z >> 4, h = z & 15;
  const int i0 = blockIdx.y * 64;
  const int ar = lane & 15, q4 = lane >> 4;
  const int myrow = i0 + wv * 16;

  // Q fragments (A-layout): row = myrow + ar, k = kd*32 + q4*8
  const long qoff = ((long)(myrow + ar) * 16 + b) * 1024 + h * 64 + q4 * 8;
  f16x8 quf[2], qvf[2];
  quf[0] = *(const f16x8*)&qu[qoff];
  quf[1] = *(const f16x8*)&qu[qoff + 32];
  qvf[0] = *(const f16x8*)&qv[qoff];
  qvf[1] = *(const f16x8*)&qv[qoff + 32];

  f32x4 o[4] = {};
  float mrow[4], lrow[4];
#pragma unroll
  for (int r = 0; r < 4; ++r) { mrow[r] = -3e38f; lrow[r] = 0.f; }

  const int ntiles = (i0 + 575 + 128) >> 7;

  for (int t = 0; t < ntiles; ++t) {
    const int j0 = t * 128;
    __builtin_amdgcn_s_barrier();  // all reads of Kl/Vl from prev tile done
    // ---- stage K-tile / V-tile (linear LDS dest, pre-swizzled source) ----
#pragma unroll
    for (int it = 0; it < 4; ++it) {
      const int ch = it * 256 + wv * 64 + lane;
      const int kr = ch >> 3, ks = ch & 7;
      gload16(kvb + ((long)(j0 + kr) * 16 + b) * 2048 + h * 64 + (ks ^ (kr & 7)) * 8,
              (char*)&Kl[0][0] + (it * 256 + wv * 64) * 16);
    }
#pragma unroll
    for (int it = 0; it < 4; ++it) {
      const int ch = it * 256 + wv * 64 + lane;
      const int vd = ch >> 4, vs = ch & 15;
      gload16(vT + ((long)z * 64 + vd) * 1024 + j0 + (vs ^ (vd & 7)) * 8,
              (char*)&Vl[0][0] + (it * 256 + wv * 64) * 16);
    }
    asm volatile("s_waitcnt vmcnt(0)" ::: "memory");
    __builtin_amdgcn_s_barrier();

    // ---- content scores: C[iloc][jloc] (16 x 128 per wave) ----
    f32x4 acc_c[8] = {};
#pragma unroll
    for (int kd = 0; kd < 2; ++kd)
#pragma unroll
      for (int nf = 0; nf < 8; ++nf) {
        const int j = nf * 16 + ar;
        const int phys = (kd * 4 + q4) ^ (j & 7);
        const f16x8 kf = *(const f16x8*)&Kl[j][phys * 8];
        acc_c[nf] = __builtin_amdgcn_mfma_f32_16x16x32_f16(quf[kd], kf, acc_c[nf], 0, 0, 0);
      }

    // ---- position band: P[iloc][band 0..191], R direct from global ----
    const int jjb = j0 - i0 + 448;
    f32x4 acc_p[12] = {};
#pragma unroll
    for (int kd = 0; kd < 2; ++kd)
#pragma unroll
      for (int jf = 0; jf < 12; ++jf) {
        int jjr = jjb + jf * 16 + ar;
        if (jjr > 1023) jjr = 1023;  // clamped rows feed only masked cols
        const f16x8 rf = *(const f16x8*)&rb[(long)jjr * 1024 + h * 64 + kd * 32 + q4 * 8];
        acc_p[jf] = __builtin_amdgcn_mfma_f32_16x16x32_f16(qvf[kd], rf, acc_p[jf], 0, 0, 0);
      }
    // write band (wave-private rows)
#pragma unroll
    for (int jf = 0; jf < 12; ++jf)
#pragma unroll
      for (int r = 0; r < 4; ++r)
        Pband[wv * 16 + q4 * 4 + r][jf * 16 + ar] = (h16)acc_p[jf][r];

    // ---- assemble S, online softmax ----
    float p[8][4];
#pragma unroll
    for (int nf = 0; nf < 8; ++nf)
#pragma unroll
      for (int r = 0; r < 4; ++r) {
        const int iloc = q4 * 4 + r;
        const int jloc = nf * 16 + ar;
        const int band = jloc - (wv * 16 + iloc) + 63;
        const float pv = (float)Pband[wv * 16 + iloc][band];
        float sv = (acc_c[nf][r] + pv) * 0.125f;
        const bool ok = (j0 + jloc) <= (myrow + iloc + 512);
        p[nf][r] = ok ? sv : -3e38f;
      }
#pragma unroll
    for (int r = 0; r < 4; ++r) {
      float tm = -3e38f;
#pragma unroll
      for (int nf = 0; nf < 8; ++nf) tm = fmaxf(tm, p[nf][r]);
      tm = fmaxf(tm, __shfl_xor(tm, 1));
      tm = fmaxf(tm, __shfl_xor(tm, 2));
      tm = fmaxf(tm, __shfl_xor(tm, 4));
      tm = fmaxf(tm, __shfl_xor(tm, 8));
      const float mn = fmaxf(mrow[r], tm);
      const float sc = __expf(mrow[r] - mn);
      mrow[r] = mn;
      float ts = 0.f;
#pragma unroll
      for (int nf = 0; nf < 8; ++nf) {
        const float e = __expf(p[nf][r] - mn);
        p[nf][r] = e;
        ts += e;
      }
      ts += __shfl_xor(ts, 1);
      ts += __shfl_xor(ts, 2);
      ts += __shfl_xor(ts, 4);
      ts += __shfl_xor(ts, 8);
      lrow[r] = lrow[r] * sc + ts;
#pragma unroll
      for (int v = 0; v < 4; ++v) o[v][r] *= sc;
    }

    // ---- P -> A-layout via wave-private LDS, then PV ----
#pragma unroll
    for (int nf = 0; nf < 8; ++nf)
#pragma unroll
      for (int r = 0; r < 4; ++r) {
        const int iloc = q4 * 4 + r, jloc = nf * 16 + ar;
        Plds[wv][iloc][((jloc >> 3) ^ (iloc & 7)) * 8 + (jloc & 7)] = (h16)p[nf][r];
      }
#pragma unroll
    for (int ks = 0; ks < 4; ++ks) {
      const f16x8 pa = *(const f16x8*)&Plds[wv][ar][((ks * 4 + q4) ^ (ar & 7)) * 8];
#pragma unroll
      for (int vnf = 0; vnf < 4; ++vnf) {
        const int d = vnf * 16 + ar;
        const f16x8 vb = *(const f16x8*)&Vl[d][((ks * 4 + q4) ^ (d & 7)) * 8];
        o[vnf] = __builtin_amdgcn_mfma_f32_16x16x32_f16(pa, vb, o[vnf], 0, 0, 0);
      }
    }
  }

  // ---- epilogue ----
#pragma unroll
  for (int vnf = 0; vnf < 4; ++vnf)
#pragma unroll
    for (int r = 0; r < 4; ++r) {
      const int i_ = myrow + q4 * 4 + r;
      attn[((long)i_ * 16 + b) * 1024 + h * 64 + vnf * 16 + ar] =
          (h16)(o[vnf][r] / lrow[r]);
    }
}

// ---------------------------------------------------------------------------
__global__ __launch_bounds__(256) void wtrans_k(const float* __restrict__ in,
                                                h16* __restrict__ out, int K, int N) {
  __shared__ float t[32][33];
  const int tx = threadIdx.x & 31, ty = threadIdx.x >> 5;
  const int n0 = blockIdx.x * 32, k0 = blockIdx.y * 32;
#pragma unroll
  for (int j = 0; j < 32; j += 8)
    t[ty + j][tx] = in[(long)(k0 + ty + j) * N + n0 + tx];
  __syncthreads();
#pragma unroll
  for (int j = 0; j < 32; j += 8)
    out[(long)(n0 + ty + j) * K + k0 + tx] = (h16)t[tx][ty + j];
}

__global__ __launch_bounds__(256) void cast_k(const float* __restrict__ in,
                                              h16* __restrict__ out, long n4) {
  const long i = (long)blockIdx.x * 256 + threadIdx.x;
  if (i >= n4) return;
  const float4 v = ((const float4*)in)[i];
  f16x4 o;
  o[0] = (h16)v.x; o[1] = (h16)v.y; o[2] = (h16)v.z; o[3] = (h16)v.w;
  ((f16x4*)out)[i] = o;
}

__global__ void addbias_k(const float* __restrict__ bq, const float* __restrict__ u,
                          const float* __restrict__ v, float* __restrict__ qu,
                          float* __restrict__ qv) {
  const int c = blockIdx.x * 256 + threadIdx.x;
  if (c < 1024) { qu[c] = bq[c] + u[c]; qv[c] = bq[c] + v[c]; }
}

__global__ __launch_bounds__(256) void zero_out_k(float* __restrict__ out, long n) {
  const long i = (long)blockIdx.x * 256 + threadIdx.x;
  if (i < n) out[i] = 0.f;
}

__global__ __launch_bounds__(256) void ln_k(const float* __restrict__ src0,
                                            const float* __restrict__ src1, int rows0,
                                            const float* __restrict__ g,
                                            const float* __restrict__ b,
                                            h16* __restrict__ out) {
  const int row = blockIdx.x, tid = threadIdx.x;
  const float* src = (row < rows0) ? (src0 + (long)row * 1024)
                                   : (src1 + (long)(row - rows0) * 1024);
  const float4 x = ((const float4*)src)[tid];
  float s = x.x + x.y + x.z + x.w;
  float sq = x.x * x.x + x.y * x.y + x.z * x.z + x.w * x.w;
#pragma unroll
  for (int o = 32; o > 0; o >>= 1) { s += __shfl_down(s, o); sq += __shfl_down(sq, o); }
  __shared__ float red[8];
  const int lane = tid & 63, w = tid >> 6;
  if (lane == 0) { red[w] = s; red[4 + w] = sq; }
  __syncthreads();
  s = red[0] + red[1] + red[2] + red[3];
  sq = red[4] + red[5] + red[6] + red[7];
  const float mu = s * (1.f / 1024.f);
  const float inv = rsqrtf(sq * (1.f / 1024.f) - mu * mu + 1e-5f);
  const float4 gg = ((const float4*)g)[tid], bb = ((const float4*)b)[tid];
  f16x4 o;
  o[0] = (h16)((x.x - mu) * inv * gg.x + bb.x);
  o[1] = (h16)((x.y - mu) * inv * gg.y + bb.y);
  o[2] = (h16)((x.z - mu) * inv * gg.z + bb.z);
  o[3] = (h16)((x.w - mu) * inv * gg.w + bb.w);
  ((f16x4*)(out + (long)row * 1024))[tid] = o;
}

// value: kv[(j*16+b)*2048 + 1024 + h*64 + d] -> vT[(z*64+d)*1024 + j], z=b*16+h
__global__ __launch_bounds__(256) void vtrans_k(const h16* __restrict__ kv,
                                                h16* __restrict__ vT) {
  const int z = blockIdx.y, b = z >> 4, h = z & 15;
  const int j0 = blockIdx.x * 64;
  __shared__ h16 t[64][72];
  const int jj = threadIdx.x >> 3, c = threadIdx.x & 7;
#pragma unroll
  for (int half = 0; half < 2; ++half) {
    const int j = jj + half * 32;
    const f16x8 v = *(const f16x8*)(kv + ((long)(j0 + j) * 16 + b) * 2048 + 1024 + h * 64 + c * 8);
    *(f16x8*)&t[j][c * 8] = v;
  }
  __syncthreads();
#pragma unroll
  for (int half = 0; half < 2; ++half) {
    const int d = jj + half * 32;
    f16x8 o;
#pragma unroll
    for (int k = 0; k < 8; ++k) o[k] = t[c * 8 + k][d];
    *(f16x8*)(vT + ((long)z * 64 + d) * 1024 + j0 + c * 8) = o;
  }
}

__global__ __launch_bounds__(256) void gru_rx_k(const float* __restrict__ T,
                                                const float* __restrict__ x,
                                                h16* __restrict__ rx) {
  const long i = (long)blockIdx.x * 256 + threadIdx.x;
  const long row = i >> 8;
  const int c4 = (int)(i & 255);
  const float4 t = *((const float4*)(T + row * 3072) + c4);
  const float4 xx = ((const float4*)x)[i];
  f16x4 o;
  o[0] = (h16)(xx.x / (1.f + __expf(-t.x)));
  o[1] = (h16)(xx.y / (1.f + __expf(-t.y)));
  o[2] = (h16)(xx.z / (1.f + __expf(-t.z)));
  o[3] = (h16)(xx.w / (1.f + __expf(-t.w)));
  ((f16x4*)rx)[i] = o;
}

__global__ __launch_bounds__(256) void gru_out_k(const float* __restrict__ T,
                                                 const float* __restrict__ x,
                                                 const float* __restrict__ bg,
                                                 float* __restrict__ outf,
                                                 h16* __restrict__ outh) {
  const long i = (long)blockIdx.x * 256 + threadIdx.x;
  const long row = i >> 8;
  const int c4 = (int)(i & 255);
  const float4 tz = *((const float4*)(T + row * 3072 + 1024) + c4);
  const float4 th = *((const float4*)(T + row * 3072 + 2048) + c4);
  const float4 xx = ((const float4*)x)[i];
  const float4 bb = ((const float4*)bg)[c4];
  float4 o;
  {
    const float z0 = 1.f / (1.f + __expf(-(tz.x - bb.x)));
    const float z1 = 1.f / (1.f + __expf(-(tz.y - bb.y)));
    const float z2 = 1.f / (1.f + __expf(-(tz.z - bb.z)));
    const float z3 = 1.f / (1.f + __expf(-(tz.w - bb.w)));
    o.x = (1.f - z0) * xx.x + z0 * tanhf(th.x);
    o.y = (1.f - z1) * xx.y + z1 * tanhf(th.y);
    o.z = (1.f - z2) * xx.z + z2 * tanhf(th.z);
    o.w = (1.f - z3) * xx.w + z3 * tanhf(th.w);
  }
  ((float4*)outf)[i] = o;
  if (outh != nullptr) {
    f16x4 oh;
    oh[0] = (h16)o.x; oh[1] = (h16)o.y; oh[2] = (h16)o.z; oh[3] = (h16)o.w;
    ((f16x4*)outh)[i] = oh;
  }
}

// ---------------------------------------------------------------------------
extern "C" void kernel_launch(void* const* d_in, const int* in_sizes, int n_in,
                              void* d_out, int out_size, void* d_ws, size_t ws_size,
                              hipStream_t stream) {
  const float* inputs = (const float*)d_in[0];
  const float* pos    = (const float*)d_in[1];
  const float* u      = (const float*)d_in[2];
  const float* v      = (const float*)d_in[3];
  const float* memory = (const float*)d_in[4];
  const float* Wkv = (const float*)d_in[6];  const float* bkv = (const float*)d_in[7];
  const float* Wq  = (const float*)d_in[8];  const float* bq  = (const float*)d_in[9];
  const float* Wo  = (const float*)d_in[10]; const float* bo  = (const float*)d_in[11];
  const float* Wp  = (const float*)d_in[12]; const float* bp  = (const float*)d_in[13];
  const float* ln1_g = (const float*)d_in[14]; const float* ln1_b = (const float*)d_in[15];
  const float* ln2_g = (const float*)d_in[16]; const float* ln2_b = (const float*)d_in[17];
  const float* W1 = (const float*)d_in[18]; const float* b1 = (const float*)d_in[19];
  const float* W2 = (const float*)d_in[20]; const float* b2 = (const float*)d_in[21];
  const float* g1_W = (const float*)d_in[22]; const float* g1_U = (const float*)d_in[23];
  const float* g1_bg = (const float*)d_in[24];
  const float* g2_W = (const float*)d_in[25]; const float* g2_U = (const float*)d_in[26];
  const float* g2_bg = (const float*)d_in[27];
  (void)in_sizes; (void)n_in;

  const size_t MB = 1u << 20;
  const size_t NEEDED = 247 * MB;
  const dim3 blk(256);
  if (ws_size < NEEDED) {
    zero_out_k<<<(out_size + 255) / 256, blk, 0, stream>>>((float*)d_out, out_size);
    return;
  }

  char* w = (char*)d_ws;
  h16* WoT   = (h16*)(w + 0 * MB);
  h16* W1T   = (h16*)(w + 2 * MB);
  h16* W2T   = (h16*)(w + 10 * MB);
  h16* g1Wb  = (h16*)(w + 18 * MB);
  h16* g1Ub  = (h16*)(w + 24 * MB);
  h16* g2Wb  = (h16*)(w + 30 * MB);
  h16* g2Ub  = (h16*)(w + 36 * MB);
  h16* WkvT  = (h16*)(w + 42 * MB);
  h16* WqT   = (h16*)(w + 46 * MB);
  h16* WpT   = (h16*)(w + 48 * MB);
  h16* posb  = (h16*)(w + 50 * MB);
  float* bias_qu = (float*)(w + 52 * MB);
  float* bias_qv = (float*)(w + 52 * MB + 8192);
  h16* xb    = (h16*)(w + 53 * MB);
  h16* x1    = (h16*)(w + 69 * MB);
  char* Rbig =        w + 101 * MB;
  h16* qu    = (h16*)(w + 197 * MB);
  h16* qv    = (h16*)(w + 213 * MB);
  h16* rb    = (h16*)(w + 229 * MB);
  h16* attn  = (h16*)(w + 231 * MB);

  h16*   kvb  = (h16*)Rbig;                   // 64 MB, live through attention
  float* Tall = (float*)Rbig;                 // 96 MB, GRU (kvb dead)
  h16*   h1   = (h16*)Rbig;                   // MLP hidden
  h16*   vT   = x1;                           // x1 dead after q GEMM
  h16*   a1   = qu;
  h16*   rx1  = qv;
  float* o1f  = (float*)qu;
  h16*   o1b  = attn;
  h16*   x2   = x1;
  h16*   m2   = x1 + 8L * 1024 * 1024;
  h16*   rx2  = x1;

  // ---- weight prep ----
  wtrans_k<<<dim3(64, 32), blk, 0, stream>>>(Wkv, WkvT, 1024, 2048);
  wtrans_k<<<dim3(32, 32), blk, 0, stream>>>(Wq, WqT, 1024, 1024);
  wtrans_k<<<dim3(32, 32), blk, 0, stream>>>(Wo, WoT, 1024, 1024);
  wtrans_k<<<dim3(32, 32), blk, 0, stream>>>(Wp, WpT, 1024, 1024);
  wtrans_k<<<dim3(128, 32), blk, 0, stream>>>(W1, W1T, 1024, 4096);
  wtrans_k<<<dim3(32, 128), blk, 0, stream>>>(W2, W2T, 4096, 1024);
  cast_k<<<3072, blk, 0, stream>>>(g1_W, g1Wb, 786432);
  cast_k<<<3072, blk, 0, stream>>>(g1_U, g1Ub, 786432);
  cast_k<<<3072, blk, 0, stream>>>(g2_W, g2Wb, 786432);
  cast_k<<<3072, blk, 0, stream>>>(g2_U, g2Ub, 786432);
  cast_k<<<1024, blk, 0, stream>>>(pos, posb, 262144);
  cast_k<<<8192, blk, 0, stream>>>(inputs, xb, 2097152);
  addbias_k<<<4, blk, 0, stream>>>(bq, u, v, bias_qu, bias_qv);

  // ---- ln1 ----
  ln_k<<<16384, blk, 0, stream>>>(memory, inputs, 8192, ln1_g, ln1_b, x1);

  // ---- projections ----
  gemm_k<128, 128, 2, 2, F_OBF | F_BIAS><<<dim3(128, 16, 1), blk, 0, stream>>>(
      x1, WkvT, kvb, nullptr, bkv, nullptr, 1024, 1024, 1024, 2048, 0, 0, 0, 0, 0, 0);
  gemm_k<128, 128, 2, 2, F_OBF | F_BIAS | F_DUAL><<<dim3(64, 8, 1), blk, 0, stream>>>(
      x1 + 8192L * 1024, WqT, qu, qv, bias_qu, bias_qv, 1024, 1024, 1024, 1024, 0, 0, 0, 0, 0, 0);
  gemm_k<128, 128, 2, 2, F_OBF | F_BIAS><<<dim3(8, 8, 1), blk, 0, stream>>>(
      posb, WpT, rb, nullptr, bp, nullptr, 1024, 1024, 1024, 1024, 0, 0, 0, 0, 0, 0);
  vtrans_k<<<dim3(16, 256), blk, 0, stream>>>(kvb, vT);

  // ---- fused attention (one launch; bid%8 == z%8 keeps a z on one XCD) ----
  fattn_k<<<dim3(256, 8), blk, 0, stream>>>(qu, qv, kvb, vT, rb, attn);

  // ---- output projection + relu -> a1 ----
  gemm_k<128, 128, 2, 2, F_OBF | F_BIAS | F_RELU><<<dim3(64, 8, 1), blk, 0, stream>>>(
      attn, WoT, a1, nullptr, bo, nullptr, 1024, 1024, 1024, 1024, 0, 0, 0, 0, 0, 0);

  // ---- GRU gate 1: x = inputs, y = a1 ----
  gemm_k<128, 128, 2, 2, 0><<<dim3(64, 24, 1), blk, 0, stream>>>(
      a1, g1Wb, Tall, nullptr, nullptr, nullptr, 1024, 1024, 1024, 3072, 0, 0, 0, 0, 0, 0);
  gemm_k<128, 128, 2, 2, F_ACC><<<dim3(64, 16, 1), blk, 0, stream>>>(
      xb, g1Ub, Tall, nullptr, nullptr, nullptr, 1024, 1024, 1024, 3072, 0, 0, 0, 0, 0, 0);
  gru_rx_k<<<8192, blk, 0, stream>>>(Tall, inputs, rx1);
  gemm_k<128, 128, 2, 2, F_ACC><<<dim3(64, 8, 1), blk, 0, stream>>>(
      rx1, g1Ub + 2L * 1024 * 1024, Tall + 2048, nullptr, nullptr, nullptr,
      1024, 1024, 1024, 3072, 0, 0, 0, 0, 0, 0);
  gru_out_k<<<8192, blk, 0, stream>>>(Tall, inputs, g1_bg, o1f, o1b);

  // ---- ln2 + MLP ----
  ln_k<<<8192, blk, 0, stream>>>(o1f, o1f, 8192, ln2_g, ln2_b, x2);
  gemm_k<128, 128, 2, 2, F_OBF | F_BIAS | F_RELU><<<dim3(64, 32, 1), blk, 0, stream>>>(
      x2, W1T, h1, nullptr, b1, nullptr, 1024, 1024, 1024, 4096, 0, 0, 0, 0, 0, 0);
  gemm_k<128, 128, 2, 2, F_OBF | F_BIAS | F_RELU><<<dim3(64, 8, 1), blk, 0, stream>>>(
      h1, W2T, m2, nullptr, b2, nullptr, 4096, 4096, 4096, 1024, 0, 0, 0, 0, 0, 0);

  // ---- GRU gate 2: x = o1, y = m2 -> d_out ----
  gemm_k<128, 128, 2, 2, 0><<<dim3(64, 24, 1), blk, 0, stream>>>(
      m2, g2Wb, Tall, nullptr, nullptr, nullptr, 1024, 1024, 1024, 3072, 0, 0, 0, 0, 0, 0);
  gemm_k<128, 128, 2, 2, F_ACC><<<dim3(64, 16, 1), blk, 0, stream>>>(
      o1b, g2Ub, Tall, nullptr, nullptr, nullptr, 1024, 1024, 1024, 3072, 0, 0, 0, 0, 0, 0);
  gru_rx_k<<<8192, blk, 0, stream>>>(Tall, o1f, rx2);
  gemm_k<128, 128, 2, 2, F_ACC><<<dim3(64, 8, 1), blk, 0, stream>>>(
      rx2, g2Ub + 2L * 1024 * 1024, Tall + 2048, nullptr, nullptr, nullptr,
      1024, 1024, 1024, 3072, 0, 0, 0, 0, 0, 0);
  gru_out_k<<<8192, blk, 0, stream>>>(Tall, o1f, g2_bg, (float*)d_out, nullptr);
}

// Round 6
// 1191.024 us; speedup vs baseline: 1.4583x; 1.0830x over previous
//
// GatedTransformerXLLayer — MI355X (gfx950) — round 6:
//   fattn: per-wave 144-wide band (9 jf vs 12), Pband/Plds union into
//   per-wave Psc -> LDS 52.5 KB -> 3 blocks/CU; stride 164 anti-conflict.
//   thin GEMMs (q/Wo/W2/rx, formerly grid 512 = 2 blk/CU): 64x128 tiles.
//
// D=1024 H=16 HD=64 HID=4096 CUR=512 PREV=512 FULL=1024 BS=16

#include <hip/hip_runtime.h>
#include <stdint.h>

typedef _Float16 h16;
typedef __attribute__((ext_vector_type(8))) _Float16 f16x8;
typedef __attribute__((ext_vector_type(4))) _Float16 f16x4;
typedef __attribute__((ext_vector_type(4))) float f32x4;

enum { F_OBF = 1, F_BIAS = 2, F_RELU = 4, F_ACC = 8, F_DUAL = 16 };

static __device__ __forceinline__ void gload16(const void* g, void* l) {
  __builtin_amdgcn_global_load_lds((__attribute__((address_space(1))) void*)g,
                                   (__attribute__((address_space(3))) void*)l,
                                   16, 0, 0);
}

// ---------------------------------------------------------------------------
// Generic MFMA GEMM: C = A(MxK) @ Bt(NxK)^T, fp16 in, f32 accum.
// T2 swizzle (pre-permuted source), 3-buf counted-vmcnt pipeline.
// ---------------------------------------------------------------------------
template <int BM, int BN, int WAVES_M, int WAVES_N, int FLAGS>
__global__ __launch_bounds__(256) void gemm_k(
    const h16* __restrict__ A, const h16* __restrict__ B,
    void* __restrict__ Cv, void* __restrict__ C2v,
    const float* __restrict__ bias, const float* __restrict__ bias2,
    int K, int lda, int ldb, int ldc,
    long sAb, long sAh, long sBb, long sBh, long sCb, long sCh) {
  constexpr int BK = 32;
  constexpr int WM = BM / WAVES_M, WN = BN / WAVES_N;
  constexpr int MF = WM / 16, NF = WN / 16;
  constexpr int LPS = BM / 64 + BN / 64;
  __shared__ h16 Al[3][BM][BK];
  __shared__ h16 Bl[3][BN][BK];

  const int tid = threadIdx.x, lane = tid & 63, wid = tid >> 6;
  const int wm = wid / WAVES_N, wn = wid % WAVES_N;
  const int z = blockIdx.z, zb = z >> 4, zh = z & 15;
  const h16* Ab = A + zb * sAb + zh * sAh + (long)blockIdx.x * BM * lda;
  const h16* Bb = B + zb * sBb + zh * sBh + (long)blockIdx.y * BN * ldb;

  const int srow = lane >> 2;
  const int skc = (((lane & 3) ^ ((lane >> 3) & 3)) * 8);

  auto stage = [&](int buf, int k0) {
#pragma unroll
    for (int t = 0; t < BM / 64; ++t) {
      const int ii = wid + t * 4;
      gload16(Ab + (long)(ii * 16 + srow) * lda + k0 + skc, &Al[buf][ii * 16][0]);
    }
#pragma unroll
    for (int t = 0; t < BN / 64; ++t) {
      const int ii = wid + t * 4;
      gload16(Bb + (long)(ii * 16 + srow) * ldb + k0 + skc, &Bl[buf][ii * 16][0]);
    }
  };

  f32x4 acc[MF][NF] = {};
  const int nk = K / BK;
  const int ar = lane & 15, ls = lane >> 4;

  stage(0, 0);
  if (nk > 1) stage(1, BK);
  for (int kt = 0; kt < nk; ++kt) {
    if (kt == nk - 1) {
      asm volatile("s_waitcnt vmcnt(0)" ::: "memory");
    } else if constexpr (LPS == 4) {
      asm volatile("s_waitcnt vmcnt(4)" ::: "memory");
    } else if constexpr (LPS == 3) {
      asm volatile("s_waitcnt vmcnt(3)" ::: "memory");
    } else {
      asm volatile("s_waitcnt vmcnt(0)" ::: "memory");
    }
    __builtin_amdgcn_s_barrier();
    asm volatile("" ::: "memory");
    if (kt + 2 < nk) stage((kt + 2) % 3, (kt + 2) * BK);
    const int cur = kt % 3;
    f16x8 af[MF], bv[NF];
#pragma unroll
    for (int m = 0; m < MF; ++m) {
      const int R = wm * WM + m * 16 + ar;
      af[m] = *(const f16x8*)&Al[cur][R][(ls ^ ((R >> 1) & 3)) * 8];
    }
#pragma unroll
    for (int n = 0; n < NF; ++n) {
      const int R = wn * WN + n * 16 + ar;
      bv[n] = *(const f16x8*)&Bl[cur][R][(ls ^ ((R >> 1) & 3)) * 8];
    }
#pragma unroll
    for (int m = 0; m < MF; ++m)
#pragma unroll
      for (int n = 0; n < NF; ++n)
        acc[m][n] = __builtin_amdgcn_mfma_f32_16x16x32_f16(af[m], bv[n], acc[m][n], 0, 0, 0);
  }

  const long coff = (long)zb * sCb + (long)zh * sCh;
#pragma unroll
  for (int m = 0; m < MF; ++m) {
#pragma unroll
    for (int n = 0; n < NF; ++n) {
      const int col = blockIdx.y * BN + wn * WN + n * 16 + ar;
      float bv1 = 0.f, bv2 = 0.f;
      if (FLAGS & F_BIAS) bv1 = bias[col];
      if (FLAGS & F_DUAL) bv2 = bias2[col];
#pragma unroll
      for (int r = 0; r < 4; ++r) {
        const int row = blockIdx.x * BM + wm * WM + m * 16 + (lane >> 4) * 4 + r;
        float val = acc[m][n][r] + bv1;
        if (FLAGS & F_RELU) val = fmaxf(val, 0.f);
        if constexpr ((FLAGS & F_ACC) != 0) {
          float* p = (float*)Cv + coff + (long)row * ldc + col;
          *p = *p + val;
        } else if constexpr ((FLAGS & F_OBF) != 0) {
          ((h16*)Cv)[coff + (long)row * ldc + col] = (h16)val;
          if constexpr ((FLAGS & F_DUAL) != 0)
            ((h16*)C2v)[coff + (long)row * ldc + col] = (h16)(acc[m][n][r] + bv2);
        } else {
          ((float*)Cv)[coff + (long)row * ldc + col] = val;
        }
      }
    }
  }
}

// ---------------------------------------------------------------------------
// Fused Transformer-XL attention, round-6 version.
// Per block: (z = b*16+h, 64-row i-tile); per wave: 16 rows.
// Position band is per-wave: jbase = j0 - myrow + 496, width 144 (9 jf).
// Psc[wv] serves as band scratch then P A-layout scratch (wave-private,
// in-order DS pipe -> no barrier needed).
// ---------------------------------------------------------------------------
__global__ __launch_bounds__(256) void fattn_k(
    const h16* __restrict__ qu, const h16* __restrict__ qv,
    const h16* __restrict__ kvb, const h16* __restrict__ vT,
    const h16* __restrict__ rb, h16* __restrict__ attn) {
  __shared__ h16 Kl[128][64];      // [j][d]   phys slot = (d_slot) ^ (j&7)
  __shared__ h16 Vl[64][128];      // [d][j]   phys slot = (j_slot) ^ (d&7)
  __shared__ h16 Psc[4][16][164];  // per-wave: band scores / P A-layout

  const int tid = threadIdx.x, lane = tid & 63, wv = tid >> 6;
  const int z = blockIdx.x, b = z >> 4, h = z & 15;
  const int i0 = blockIdx.y * 64;
  const int ar = lane & 15, q4 = lane >> 4;
  const int myrow = i0 + wv * 16;

  const long qoff = ((long)(myrow + ar) * 16 + b) * 1024 + h * 64 + q4 * 8;
  f16x8 quf[2], qvf[2];
  quf[0] = *(const f16x8*)&qu[qoff];
  quf[1] = *(const f16x8*)&qu[qoff + 32];
  qvf[0] = *(const f16x8*)&qv[qoff];
  qvf[1] = *(const f16x8*)&qv[qoff + 32];

  f32x4 o[4] = {};
  float mrow[4], lrow[4];
#pragma unroll
  for (int r = 0; r < 4; ++r) { mrow[r] = -3e38f; lrow[r] = 0.f; }

  const int ntiles = (i0 + 575 + 128) >> 7;

  for (int t = 0; t < ntiles; ++t) {
    const int j0 = t * 128;
    __builtin_amdgcn_s_barrier();  // Kl/Vl reads of prev tile complete
#pragma unroll
    for (int it = 0; it < 4; ++it) {
      const int ch = it * 256 + wv * 64 + lane;
      const int kr = ch >> 3, ks = ch & 7;
      gload16(kvb + ((long)(j0 + kr) * 16 + b) * 2048 + h * 64 + (ks ^ (kr & 7)) * 8,
              (char*)&Kl[0][0] + (it * 256 + wv * 64) * 16);
    }
#pragma unroll
    for (int it = 0; it < 4; ++it) {
      const int ch = it * 256 + wv * 64 + lane;
      const int vd = ch >> 4, vs = ch & 15;
      gload16(vT + ((long)z * 64 + vd) * 1024 + j0 + (vs ^ (vd & 7)) * 8,
              (char*)&Vl[0][0] + (it * 256 + wv * 64) * 16);
    }
    asm volatile("s_waitcnt vmcnt(0)" ::: "memory");
    __builtin_amdgcn_s_barrier();

    // ---- content scores ----
    f32x4 acc_c[8] = {};
#pragma unroll
    for (int kd = 0; kd < 2; ++kd)
#pragma unroll
      for (int nf = 0; nf < 8; ++nf) {
        const int j = nf * 16 + ar;
        const int phys = (kd * 4 + q4) ^ (j & 7);
        const f16x8 kf = *(const f16x8*)&Kl[j][phys * 8];
        acc_c[nf] = __builtin_amdgcn_mfma_f32_16x16x32_f16(quf[kd], kf, acc_c[nf], 0, 0, 0);
      }

    // ---- position band (per-wave, width 144): jj = jbase + band ----
    const int jbase = j0 - myrow + 496;
    f32x4 acc_p[9] = {};
#pragma unroll
    for (int kd = 0; kd < 2; ++kd)
#pragma unroll
      for (int jf = 0; jf < 9; ++jf) {
        int jjr = jbase + jf * 16 + ar;
        if (jjr > 1023) jjr = 1023;  // clamped rows feed only masked cols
        const f16x8 rf = *(const f16x8*)&rb[(long)jjr * 1024 + h * 64 + kd * 32 + q4 * 8];
        acc_p[jf] = __builtin_amdgcn_mfma_f32_16x16x32_f16(qvf[kd], rf, acc_p[jf], 0, 0, 0);
      }
#pragma unroll
    for (int jf = 0; jf < 9; ++jf)
#pragma unroll
      for (int r = 0; r < 4; ++r)
        Psc[wv][q4 * 4 + r][jf * 16 + ar] = (h16)acc_p[jf][r];

    // ---- assemble S, online softmax ----
    float p[8][4];
#pragma unroll
    for (int nf = 0; nf < 8; ++nf)
#pragma unroll
      for (int r = 0; r < 4; ++r) {
        const int iloc = q4 * 4 + r;
        const int jloc = nf * 16 + ar;
        const int band = jloc - iloc + 15;  // in [0,142]
        const float pv = (float)Psc[wv][iloc][band];
        float sv = (acc_c[nf][r] + pv) * 0.125f;
        const bool ok = (j0 + jloc) <= (myrow + iloc + 512);
        p[nf][r] = ok ? sv : -3e38f;
      }
#pragma unroll
    for (int r = 0; r < 4; ++r) {
      float tm = -3e38f;
#pragma unroll
      for (int nf = 0; nf < 8; ++nf) tm = fmaxf(tm, p[nf][r]);
      tm = fmaxf(tm, __shfl_xor(tm, 1));
      tm = fmaxf(tm, __shfl_xor(tm, 2));
      tm = fmaxf(tm, __shfl_xor(tm, 4));
      tm = fmaxf(tm, __shfl_xor(tm, 8));
      const float mn = fmaxf(mrow[r], tm);
      const float sc = __expf(mrow[r] - mn);
      mrow[r] = mn;
      float ts = 0.f;
#pragma unroll
      for (int nf = 0; nf < 8; ++nf) {
        const float e = __expf(p[nf][r] - mn);
        p[nf][r] = e;
        ts += e;
      }
      ts += __shfl_xor(ts, 1);
      ts += __shfl_xor(ts, 2);
      ts += __shfl_xor(ts, 4);
      ts += __shfl_xor(ts, 8);
      lrow[r] = lrow[r] * sc + ts;
#pragma unroll
      for (int v = 0; v < 4; ++v) o[v][r] *= sc;
    }

    // ---- P -> A-layout (reuse Psc[wv]; band reads already consumed) ----
#pragma unroll
    for (int nf = 0; nf < 8; ++nf)
#pragma unroll
      for (int r = 0; r < 4; ++r) {
        const int iloc = q4 * 4 + r, jloc = nf * 16 + ar;
        Psc[wv][iloc][((jloc >> 3) ^ (iloc & 7)) * 8 + (jloc & 7)] = (h16)p[nf][r];
      }
#pragma unroll
    for (int ks = 0; ks < 4; ++ks) {
      const f16x8 pa = *(const f16x8*)&Psc[wv][ar][((ks * 4 + q4) ^ (ar & 7)) * 8];
#pragma unroll
      for (int vnf = 0; vnf < 4; ++vnf) {
        const int d = vnf * 16 + ar;
        const f16x8 vb = *(const f16x8*)&Vl[d][((ks * 4 + q4) ^ (d & 7)) * 8];
        o[vnf] = __builtin_amdgcn_mfma_f32_16x16x32_f16(pa, vb, o[vnf], 0, 0, 0);
      }
    }
  }

#pragma unroll
  for (int vnf = 0; vnf < 4; ++vnf)
#pragma unroll
    for (int r = 0; r < 4; ++r) {
      const int i_ = myrow + q4 * 4 + r;
      attn[((long)i_ * 16 + b) * 1024 + h * 64 + vnf * 16 + ar] =
          (h16)(o[vnf][r] / lrow[r]);
    }
}

// ---------------------------------------------------------------------------
__global__ __launch_bounds__(256) void wtrans_k(const float* __restrict__ in,
                                                h16* __restrict__ out, int K, int N) {
  __shared__ float t[32][33];
  const int tx = threadIdx.x & 31, ty = threadIdx.x >> 5;
  const int n0 = blockIdx.x * 32, k0 = blockIdx.y * 32;
#pragma unroll
  for (int j = 0; j < 32; j += 8)
    t[ty + j][tx] = in[(long)(k0 + ty + j) * N + n0 + tx];
  __syncthreads();
#pragma unroll
  for (int j = 0; j < 32; j += 8)
    out[(long)(n0 + ty + j) * K + k0 + tx] = (h16)t[tx][ty + j];
}

__global__ __launch_bounds__(256) void cast_k(const float* __restrict__ in,
                                              h16* __restrict__ out, long n4) {
  const long i = (long)blockIdx.x * 256 + threadIdx.x;
  if (i >= n4) return;
  const float4 v = ((const float4*)in)[i];
  f16x4 o;
  o[0] = (h16)v.x; o[1] = (h16)v.y; o[2] = (h16)v.z; o[3] = (h16)v.w;
  ((f16x4*)out)[i] = o;
}

__global__ void addbias_k(const float* __restrict__ bq, const float* __restrict__ u,
                          const float* __restrict__ v, float* __restrict__ qu,
                          float* __restrict__ qv) {
  const int c = blockIdx.x * 256 + threadIdx.x;
  if (c < 1024) { qu[c] = bq[c] + u[c]; qv[c] = bq[c] + v[c]; }
}

__global__ __launch_bounds__(256) void zero_out_k(float* __restrict__ out, long n) {
  const long i = (long)blockIdx.x * 256 + threadIdx.x;
  if (i < n) out[i] = 0.f;
}

__global__ __launch_bounds__(256) void ln_k(const float* __restrict__ src0,
                                            const float* __restrict__ src1, int rows0,
                                            const float* __restrict__ g,
                                            const float* __restrict__ b,
                                            h16* __restrict__ out) {
  const int row = blockIdx.x, tid = threadIdx.x;
  const float* src = (row < rows0) ? (src0 + (long)row * 1024)
                                   : (src1 + (long)(row - rows0) * 1024);
  const float4 x = ((const float4*)src)[tid];
  float s = x.x + x.y + x.z + x.w;
  float sq = x.x * x.x + x.y * x.y + x.z * x.z + x.w * x.w;
#pragma unroll
  for (int o = 32; o > 0; o >>= 1) { s += __shfl_down(s, o); sq += __shfl_down(sq, o); }
  __shared__ float red[8];
  const int lane = tid & 63, w = tid >> 6;
  if (lane == 0) { red[w] = s; red[4 + w] = sq; }
  __syncthreads();
  s = red[0] + red[1] + red[2] + red[3];
  sq = red[4] + red[5] + red[6] + red[7];
  const float mu = s * (1.f / 1024.f);
  const float inv = rsqrtf(sq * (1.f / 1024.f) - mu * mu + 1e-5f);
  const float4 gg = ((const float4*)g)[tid], bb = ((const float4*)b)[tid];
  f16x4 o;
  o[0] = (h16)((x.x - mu) * inv * gg.x + bb.x);
  o[1] = (h16)((x.y - mu) * inv * gg.y + bb.y);
  o[2] = (h16)((x.z - mu) * inv * gg.z + bb.z);
  o[3] = (h16)((x.w - mu) * inv * gg.w + bb.w);
  ((f16x4*)(out + (long)row * 1024))[tid] = o;
}

// value: kv[(j*16+b)*2048 + 1024 + h*64 + d] -> vT[(z*64+d)*1024 + j], z=b*16+h
__global__ __launch_bounds__(256) void vtrans_k(const h16* __restrict__ kv,
                                                h16* __restrict__ vT) {
  const int z = blockIdx.y, b = z >> 4, h = z & 15;
  const int j0 = blockIdx.x * 64;
  __shared__ h16 t[64][72];
  const int jj = threadIdx.x >> 3, c = threadIdx.x & 7;
#pragma unroll
  for (int half = 0; half < 2; ++half) {
    const int j = jj + half * 32;
    const f16x8 v = *(const f16x8*)(kv + ((long)(j0 + j) * 16 + b) * 2048 + 1024 + h * 64 + c * 8);
    *(f16x8*)&t[j][c * 8] = v;
  }
  __syncthreads();
#pragma unroll
  for (int half = 0; half < 2; ++half) {
    const int d = jj + half * 32;
    f16x8 o;
#pragma unroll
    for (int k = 0; k < 8; ++k) o[k] = t[c * 8 + k][d];
    *(f16x8*)(vT + ((long)z * 64 + d) * 1024 + j0 + c * 8) = o;
  }
}

__global__ __launch_bounds__(256) void gru_rx_k(const float* __restrict__ T,
                                                const float* __restrict__ x,
                                                h16* __restrict__ rx) {
  const long i = (long)blockIdx.x * 256 + threadIdx.x;
  const long row = i >> 8;
  const int c4 = (int)(i & 255);
  const float4 t = *((const float4*)(T + row * 3072) + c4);
  const float4 xx = ((const float4*)x)[i];
  f16x4 o;
  o[0] = (h16)(xx.x / (1.f + __expf(-t.x)));
  o[1] = (h16)(xx.y / (1.f + __expf(-t.y)));
  o[2] = (h16)(xx.z / (1.f + __expf(-t.z)));
  o[3] = (h16)(xx.w / (1.f + __expf(-t.w)));
  ((f16x4*)rx)[i] = o;
}

__global__ __launch_bounds__(256) void gru_out_k(const float* __restrict__ T,
                                                 const float* __restrict__ x,
                                                 const float* __restrict__ bg,
                                                 float* __restrict__ outf,
                                                 h16* __restrict__ outh) {
  const long i = (long)blockIdx.x * 256 + threadIdx.x;
  const long row = i >> 8;
  const int c4 = (int)(i & 255);
  const float4 tz = *((const float4*)(T + row * 3072 + 1024) + c4);
  const float4 th = *((const float4*)(T + row * 3072 + 2048) + c4);
  const float4 xx = ((const float4*)x)[i];
  const float4 bb = ((const float4*)bg)[c4];
  float4 o;
  {
    const float z0 = 1.f / (1.f + __expf(-(tz.x - bb.x)));
    const float z1 = 1.f / (1.f + __expf(-(tz.y - bb.y)));
    const float z2 = 1.f / (1.f + __expf(-(tz.z - bb.z)));
    const float z3 = 1.f / (1.f + __expf(-(tz.w - bb.w)));
    o.x = (1.f - z0) * xx.x + z0 * tanhf(th.x);
    o.y = (1.f - z1) * xx.y + z1 * tanhf(th.y);
    o.z = (1.f - z2) * xx.z + z2 * tanhf(th.z);
    o.w = (1.f - z3) * xx.w + z3 * tanhf(th.w);
  }
  ((float4*)outf)[i] = o;
  if (outh != nullptr) {
    f16x4 oh;
    oh[0] = (h16)o.x; oh[1] = (h16)o.y; oh[2] = (h16)o.z; oh[3] = (h16)o.w;
    ((f16x4*)outh)[i] = oh;
  }
}

// ---------------------------------------------------------------------------
extern "C" void kernel_launch(void* const* d_in, const int* in_sizes, int n_in,
                              void* d_out, int out_size, void* d_ws, size_t ws_size,
                              hipStream_t stream) {
  const float* inputs = (const float*)d_in[0];
  const float* pos    = (const float*)d_in[1];
  const float* u      = (const float*)d_in[2];
  const float* v      = (const float*)d_in[3];
  const float* memory = (const float*)d_in[4];
  const float* Wkv = (const float*)d_in[6];  const float* bkv = (const float*)d_in[7];
  const float* Wq  = (const float*)d_in[8];  const float* bq  = (const float*)d_in[9];
  const float* Wo  = (const float*)d_in[10]; const float* bo  = (const float*)d_in[11];
  const float* Wp  = (const float*)d_in[12]; const float* bp  = (const float*)d_in[13];
  const float* ln1_g = (const float*)d_in[14]; const float* ln1_b = (const float*)d_in[15];
  const float* ln2_g = (const float*)d_in[16]; const float* ln2_b = (const float*)d_in[17];
  const float* W1 = (const float*)d_in[18]; const float* b1 = (const float*)d_in[19];
  const float* W2 = (const float*)d_in[20]; const float* b2 = (const float*)d_in[21];
  const float* g1_W = (const float*)d_in[22]; const float* g1_U = (const float*)d_in[23];
  const float* g1_bg = (const float*)d_in[24];
  const float* g2_W = (const float*)d_in[25]; const float* g2_U = (const float*)d_in[26];
  const float* g2_bg = (const float*)d_in[27];
  (void)in_sizes; (void)n_in;

  const size_t MB = 1u << 20;
  const size_t NEEDED = 247 * MB;
  const dim3 blk(256);
  if (ws_size < NEEDED) {
    zero_out_k<<<(out_size + 255) / 256, blk, 0, stream>>>((float*)d_out, out_size);
    return;
  }

  char* w = (char*)d_ws;
  h16* WoT   = (h16*)(w + 0 * MB);
  h16* W1T   = (h16*)(w + 2 * MB);
  h16* W2T   = (h16*)(w + 10 * MB);
  h16* g1Wb  = (h16*)(w + 18 * MB);
  h16* g1Ub  = (h16*)(w + 24 * MB);
  h16* g2Wb  = (h16*)(w + 30 * MB);
  h16* g2Ub  = (h16*)(w + 36 * MB);
  h16* WkvT  = (h16*)(w + 42 * MB);
  h16* WqT   = (h16*)(w + 46 * MB);
  h16* WpT   = (h16*)(w + 48 * MB);
  h16* posb  = (h16*)(w + 50 * MB);
  float* bias_qu = (float*)(w + 52 * MB);
  float* bias_qv = (float*)(w + 52 * MB + 8192);
  h16* xb    = (h16*)(w + 53 * MB);
  h16* x1    = (h16*)(w + 69 * MB);
  char* Rbig =        w + 101 * MB;
  h16* qu    = (h16*)(w + 197 * MB);
  h16* qv    = (h16*)(w + 213 * MB);
  h16* rb    = (h16*)(w + 229 * MB);
  h16* attn  = (h16*)(w + 231 * MB);

  h16*   kvb  = (h16*)Rbig;
  float* Tall = (float*)Rbig;
  h16*   h1   = (h16*)Rbig;
  h16*   vT   = x1;
  h16*   a1   = qu;
  h16*   rx1  = qv;
  float* o1f  = (float*)qu;
  h16*   o1b  = attn;
  h16*   x2   = x1;
  h16*   m2   = x1 + 8L * 1024 * 1024;
  h16*   rx2  = x1;

  // ---- weight prep ----
  wtrans_k<<<dim3(64, 32), blk, 0, stream>>>(Wkv, WkvT, 1024, 2048);
  wtrans_k<<<dim3(32, 32), blk, 0, stream>>>(Wq, WqT, 1024, 1024);
  wtrans_k<<<dim3(32, 32), blk, 0, stream>>>(Wo, WoT, 1024, 1024);
  wtrans_k<<<dim3(32, 32), blk, 0, stream>>>(Wp, WpT, 1024, 1024);
  wtrans_k<<<dim3(128, 32), blk, 0, stream>>>(W1, W1T, 1024, 4096);
  wtrans_k<<<dim3(32, 128), blk, 0, stream>>>(W2, W2T, 4096, 1024);
  cast_k<<<3072, blk, 0, stream>>>(g1_W, g1Wb, 786432);
  cast_k<<<3072, blk, 0, stream>>>(g1_U, g1Ub, 786432);
  cast_k<<<3072, blk, 0, stream>>>(g2_W, g2Wb, 786432);
  cast_k<<<3072, blk, 0, stream>>>(g2_U, g2Ub, 786432);
  cast_k<<<1024, blk, 0, stream>>>(pos, posb, 262144);
  cast_k<<<8192, blk, 0, stream>>>(inputs, xb, 2097152);
  addbias_k<<<4, blk, 0, stream>>>(bq, u, v, bias_qu, bias_qv);

  // ---- ln1 ----
  ln_k<<<16384, blk, 0, stream>>>(memory, inputs, 8192, ln1_g, ln1_b, x1);

  // ---- projections ----
  gemm_k<128, 128, 2, 2, F_OBF | F_BIAS><<<dim3(128, 16, 1), blk, 0, stream>>>(
      x1, WkvT, kvb, nullptr, bkv, nullptr, 1024, 1024, 1024, 2048, 0, 0, 0, 0, 0, 0);
  gemm_k<64, 128, 2, 2, F_OBF | F_BIAS | F_DUAL><<<dim3(128, 8, 1), blk, 0, stream>>>(
      x1 + 8192L * 1024, WqT, qu, qv, bias_qu, bias_qv, 1024, 1024, 1024, 1024, 0, 0, 0, 0, 0, 0);
  gemm_k<128, 128, 2, 2, F_OBF | F_BIAS><<<dim3(8, 8, 1), blk, 0, stream>>>(
      posb, WpT, rb, nullptr, bp, nullptr, 1024, 1024, 1024, 1024, 0, 0, 0, 0, 0, 0);
  vtrans_k<<<dim3(16, 256), blk, 0, stream>>>(kvb, vT);

  // ---- fused attention ----
  fattn_k<<<dim3(256, 8), blk, 0, stream>>>(qu, qv, kvb, vT, rb, attn);

  // ---- output projection + relu -> a1 ----
  gemm_k<64, 128, 2, 2, F_OBF | F_BIAS | F_RELU><<<dim3(128, 8, 1), blk, 0, stream>>>(
      attn, WoT, a1, nullptr, bo, nullptr, 1024, 1024, 1024, 1024, 0, 0, 0, 0, 0, 0);

  // ---- GRU gate 1 ----
  gemm_k<128, 128, 2, 2, 0><<<dim3(64, 24, 1), blk, 0, stream>>>(
      a1, g1Wb, Tall, nullptr, nullptr, nullptr, 1024, 1024, 1024, 3072, 0, 0, 0, 0, 0, 0);
  gemm_k<128, 128, 2, 2, F_ACC><<<dim3(64, 16, 1), blk, 0, stream>>>(
      xb, g1Ub, Tall, nullptr, nullptr, nullptr, 1024, 1024, 1024, 3072, 0, 0, 0, 0, 0, 0);
  gru_rx_k<<<8192, blk, 0, stream>>>(Tall, inputs, rx1);
  gemm_k<64, 128, 2, 2, F_ACC><<<dim3(128, 8, 1), blk, 0, stream>>>(
      rx1, g1Ub + 2L * 1024 * 1024, Tall + 2048, nullptr, nullptr, nullptr,
      1024, 1024, 1024, 3072, 0, 0, 0, 0, 0, 0);
  gru_out_k<<<8192, blk, 0, stream>>>(Tall, inputs, g1_bg, o1f, o1b);

  // ---- ln2 + MLP ----
  ln_k<<<8192, blk, 0, stream>>>(o1f, o1f, 8192, ln2_g, ln2_b, x2);
  gemm_k<128, 128, 2, 2, F_OBF | F_BIAS | F_RELU><<<dim3(64, 32, 1), blk, 0, stream>>>(
      x2, W1T, h1, nullptr, b1, nullptr, 1024, 1024, 1024, 4096, 0, 0, 0, 0, 0, 0);
  gemm_k<64, 128, 2, 2, F_OBF | F_BIAS | F_RELU><<<dim3(128, 8, 1), blk, 0, stream>>>(
      h1, W2T, m2, nullptr, b2, nullptr, 4096, 4096, 4096, 1024, 0, 0, 0, 0, 0, 0);

  // ---- GRU gate 2 ----
  gemm_k<128, 128, 2, 2, 0><<<dim3(64, 24, 1), blk, 0, stream>>>(
      m2, g2Wb, Tall, nullptr, nullptr, nullptr, 1024, 1024, 1024, 3072, 0, 0, 0, 0, 0, 0);
  gemm_k<128, 128, 2, 2, F_ACC><<<dim3(64, 16, 1), blk, 0, stream>>>(
      o1b, g2Ub, Tall, nullptr, nullptr, nullptr, 1024, 1024, 1024, 3072, 0, 0, 0, 0, 0, 0);
  gru_rx_k<<<8192, blk, 0, stream>>>(Tall, o1f, rx2);
  gemm_k<64, 128, 2, 2, F_ACC><<<dim3(128, 8, 1), blk, 0, stream>>>(
      rx2, g2Ub + 2L * 1024 * 1024, Tall + 2048, nullptr, nullptr, nullptr,
      1024, 1024, 1024, 3072, 0, 0, 0, 0, 0, 0);
  gru_out_k<<<8192, blk, 0, stream>>>(Tall, o1f, g2_bg, (float*)d_out, nullptr);
}

// Round 7
// 1133.231 us; speedup vs baseline: 1.5327x; 1.0510x over previous
//
// GatedTransformerXLLayer — MI355X (gfx950) — round 7:
//   + gemm2_k: 256x256 8-phase deep-pipelined GEMM (T2+T3+T4+T5 combo per
//     the m201 template): 512 thr / 8 waves (2Mx4N), per-wave 128x64, BK=64,
//     128KB LDS double-buffer, XOR-swizzle via pre-permuted gload source,
//     counted vmcnt(8) per K-tile (never 0 in steady state), raw s_barrier,
//     setprio around MFMA clusters. Staging 2 K-tiles ahead into half-regions
//     right after their last read (B-halves @P2, A-halves @P3).
//   Applied to kv / GRU-W x2 / GRU-U x2 / W1 (309 GF). N=1024 GEMMs keep the
//   old 2-phase kernel. fattn unchanged from r6.
//
// D=1024 H=16 HD=64 HID=4096 CUR=512 PREV=512 FULL=1024 BS=16

#include <hip/hip_runtime.h>
#include <stdint.h>

typedef _Float16 h16;
typedef __attribute__((ext_vector_type(8))) _Float16 f16x8;
typedef __attribute__((ext_vector_type(4))) _Float16 f16x4;
typedef __attribute__((ext_vector_type(4))) float f32x4;

enum { F_OBF = 1, F_BIAS = 2, F_RELU = 4, F_ACC = 8, F_DUAL = 16 };

#define BARRIER_MEM                                  \
  do {                                               \
    asm volatile("" ::: "memory");                   \
    __builtin_amdgcn_s_barrier();                    \
    asm volatile("" ::: "memory");                   \
  } while (0)

static __device__ __forceinline__ void gload16(const void* g, void* l) {
  __builtin_amdgcn_global_load_lds((__attribute__((address_space(1))) void*)g,
                                   (__attribute__((address_space(3))) void*)l,
                                   16, 0, 0);
}

// ---------------------------------------------------------------------------
// gemm2_k: C = A(Mx K) @ Bt(N x K)^T, 256x256 tile, 8-phase pipeline.
// Grid: 1D nwg = (M/256)*(N/256), nwg % 8 == 0 (XCD swizzle), block 512.
// LDS [2][256][64] per operand; phys 16B-slot = logical ^ (row & 7);
// source column pre-permuted so global_load_lds (linear dest) lands swizzled.
// ---------------------------------------------------------------------------
template <int FLAGS>
__global__ __launch_bounds__(512) void gemm2_k(
    const h16* __restrict__ A, const h16* __restrict__ B,
    void* __restrict__ Cv, const float* __restrict__ bias,
    int K, int lda, int ldb, int ldc, int gm) {
  __shared__ h16 Al[2][256][64];
  __shared__ h16 Bl[2][256][64];

  const int tid = threadIdx.x, lane = tid & 63, wid = tid >> 6;
  const int wr = wid >> 2, wn = wid & 3;     // 2 M-waves x 4 N-waves
  const int ar = lane & 15, q4 = lane >> 4;

  // bijective XCD swizzle (nwg % 8 == 0), then column-major tile mapping
  const int nwg = gridDim.x, cpx = nwg >> 3;
  const int bid = (blockIdx.x & 7) * cpx + (blockIdx.x >> 3);
  const int mx = bid % gm, ny = bid / gm;

  const h16* Ab = A + (long)mx * 256 * lda;
  const h16* Bb = B + (long)ny * 256 * ldb;

  // stage one half (128 rows x 64 cols) of one operand: 2 gloads per thread
  auto stageA = [&](int buf, int half, int k0) {
#pragma unroll
    for (int l = 0; l < 2; ++l) {
      const int idx = l * 512 + tid;                 // 0..1023 16B chunks
      const int row = half * 128 + (idx >> 3), sl = idx & 7;
      gload16(Ab + (long)row * lda + k0 + (sl ^ (row & 7)) * 8,
              (char*)&Al[buf][0][0] + (half * 1024 + l * 512 + wid * 64) * 16);
    }
  };
  auto stageB = [&](int buf, int half, int k0) {
#pragma unroll
    for (int l = 0; l < 2; ++l) {
      const int idx = l * 512 + tid;
      const int row = half * 128 + (idx >> 3), sl = idx & 7;
      gload16(Bb + (long)row * ldb + k0 + (sl ^ (row & 7)) * 8,
              (char*)&Bl[buf][0][0] + (half * 1024 + l * 512 + wid * 64) * 16);
    }
  };

  f32x4 acc[8][4] = {};
  const int nk = K >> 6;  // K-tiles of 64

  // ---- prologue: stage K-tiles 0 and 1 ----
  stageB(0, 0, 0); stageB(0, 1, 0); stageA(0, 0, 0); stageA(0, 1, 0);
  if (nk > 1) { stageB(1, 0, 64); stageB(1, 1, 64); stageA(1, 0, 64); stageA(1, 1, 64); }
  if (nk > 1) asm volatile("s_waitcnt vmcnt(8)" ::: "memory");
  else        asm volatile("s_waitcnt vmcnt(0)" ::: "memory");
  BARRIER_MEM;

  for (int kt = 0; kt < nk; ++kt) {
    const int b = kt & 1;
    const int k2 = (kt + 2) << 6;
    const bool pf = (kt + 2) < nk;

    // ================= P0: read A0-3 + B0-1; MFMA q0 =================
    f16x8 a0[4][2], b0[2][2];
#pragma unroll
    for (int m = 0; m < 4; ++m) {
      const int row = wr * 128 + m * 16 + ar;
#pragma unroll
      for (int ks = 0; ks < 2; ++ks)
        a0[m][ks] = *(const f16x8*)&Al[b][row][((ks * 4 + q4) ^ (row & 7)) * 8];
    }
#pragma unroll
    for (int n = 0; n < 2; ++n) {
      const int row = wn * 64 + n * 16 + ar;
#pragma unroll
      for (int ks = 0; ks < 2; ++ks)
        b0[n][ks] = *(const f16x8*)&Bl[b][row][((ks * 4 + q4) ^ (row & 7)) * 8];
    }
    BARRIER_MEM;
    __builtin_amdgcn_s_setprio(1);
#pragma unroll
    for (int m = 0; m < 4; ++m)
#pragma unroll
      for (int n = 0; n < 2; ++n)
#pragma unroll
        for (int ks = 0; ks < 2; ++ks)
          acc[m][n] = __builtin_amdgcn_mfma_f32_16x16x32_f16(a0[m][ks], b0[n][ks], acc[m][n], 0, 0, 0);
    __builtin_amdgcn_s_setprio(0);
    BARRIER_MEM;

    // ================= P1: read B2-3; MFMA q1 =================
    f16x8 b1f[2][2];
#pragma unroll
    for (int n = 0; n < 2; ++n) {
      const int row = wn * 64 + (n + 2) * 16 + ar;
#pragma unroll
      for (int ks = 0; ks < 2; ++ks)
        b1f[n][ks] = *(const f16x8*)&Bl[b][row][((ks * 4 + q4) ^ (row & 7)) * 8];
    }
    BARRIER_MEM;
    __builtin_amdgcn_s_setprio(1);
#pragma unroll
    for (int m = 0; m < 4; ++m)
#pragma unroll
      for (int n = 0; n < 2; ++n)
#pragma unroll
        for (int ks = 0; ks < 2; ++ks)
          acc[m][n + 2] = __builtin_amdgcn_mfma_f32_16x16x32_f16(a0[m][ks], b1f[n][ks], acc[m][n + 2], 0, 0, 0);
    __builtin_amdgcn_s_setprio(0);
    BARRIER_MEM;

    // ===== P2: read A4-7; stage next B halves (B of kt fully consumed) =====
    f16x8 a1f[4][2];
#pragma unroll
    for (int m = 0; m < 4; ++m) {
      const int row = wr * 128 + (m + 4) * 16 + ar;
#pragma unroll
      for (int ks = 0; ks < 2; ++ks)
        a1f[m][ks] = *(const f16x8*)&Al[b][row][((ks * 4 + q4) ^ (row & 7)) * 8];
    }
    if (pf) { stageB(b, 0, k2); stageB(b, 1, k2); }
    BARRIER_MEM;
    __builtin_amdgcn_s_setprio(1);
#pragma unroll
    for (int m = 0; m < 4; ++m)
#pragma unroll
      for (int n = 0; n < 2; ++n)
#pragma unroll
        for (int ks = 0; ks < 2; ++ks)
          acc[m + 4][n] = __builtin_amdgcn_mfma_f32_16x16x32_f16(a1f[m][ks], b0[n][ks], acc[m + 4][n], 0, 0, 0);
    __builtin_amdgcn_s_setprio(0);
    BARRIER_MEM;

    // ===== P3: stage next A halves (A of kt fully consumed); MFMA q3 =====
    if (pf) { stageA(b, 0, k2); stageA(b, 1, k2); }
    __builtin_amdgcn_s_setprio(1);
#pragma unroll
    for (int m = 0; m < 4; ++m)
#pragma unroll
      for (int n = 0; n < 2; ++n)
#pragma unroll
        for (int ks = 0; ks < 2; ++ks)
          acc[m + 4][n + 2] = __builtin_amdgcn_mfma_f32_16x16x32_f16(a1f[m][ks], b1f[n][ks], acc[m + 4][n + 2], 0, 0, 0);
    __builtin_amdgcn_s_setprio(0);
    if (pf)                 asm volatile("s_waitcnt vmcnt(8)" ::: "memory");
    else if (kt + 1 < nk)   asm volatile("s_waitcnt vmcnt(0)" ::: "memory");
    BARRIER_MEM;
  }

  // ---- epilogue ----
#pragma unroll
  for (int m = 0; m < 8; ++m) {
#pragma unroll
    for (int n = 0; n < 4; ++n) {
      const int col = ny * 256 + wn * 64 + n * 16 + ar;
      float bv1 = 0.f;
      if (FLAGS & F_BIAS) bv1 = bias[col];
#pragma unroll
      for (int r = 0; r < 4; ++r) {
        const int row = mx * 256 + wr * 128 + m * 16 + q4 * 4 + r;
        float val = acc[m][n][r] + bv1;
        if (FLAGS & F_RELU) val = fmaxf(val, 0.f);
        if constexpr ((FLAGS & F_ACC) != 0) {
          float* p = (float*)Cv + (long)row * ldc + col;
          *p = *p + val;
        } else if constexpr ((FLAGS & F_OBF) != 0) {
          ((h16*)Cv)[(long)row * ldc + col] = (h16)val;
        } else {
          ((float*)Cv)[(long)row * ldc + col] = val;
        }
      }
    }
  }
}

// ---------------------------------------------------------------------------
// Old 2-phase GEMM (kept for N=1024 shapes and r): T2 swizzle + 3-buf vmcnt.
// ---------------------------------------------------------------------------
template <int BM, int BN, int WAVES_M, int WAVES_N, int FLAGS>
__global__ __launch_bounds__(256) void gemm_k(
    const h16* __restrict__ A, const h16* __restrict__ B,
    void* __restrict__ Cv, void* __restrict__ C2v,
    const float* __restrict__ bias, const float* __restrict__ bias2,
    int K, int lda, int ldb, int ldc,
    long sAb, long sAh, long sBb, long sBh, long sCb, long sCh) {
  constexpr int BK = 32;
  constexpr int WM = BM / WAVES_M, WN = BN / WAVES_N;
  constexpr int MF = WM / 16, NF = WN / 16;
  constexpr int LPS = BM / 64 + BN / 64;
  __shared__ h16 Al[3][BM][BK];
  __shared__ h16 Bl[3][BN][BK];

  const int tid = threadIdx.x, lane = tid & 63, wid = tid >> 6;
  const int wm = wid / WAVES_N, wn = wid % WAVES_N;
  const int z = blockIdx.z, zb = z >> 4, zh = z & 15;
  const h16* Ab = A + zb * sAb + zh * sAh + (long)blockIdx.x * BM * lda;
  const h16* Bb = B + zb * sBb + zh * sBh + (long)blockIdx.y * BN * ldb;

  const int srow = lane >> 2;
  const int skc = (((lane & 3) ^ ((lane >> 3) & 3)) * 8);

  auto stage = [&](int buf, int k0) {
#pragma unroll
    for (int t = 0; t < BM / 64; ++t) {
      const int ii = wid + t * 4;
      gload16(Ab + (long)(ii * 16 + srow) * lda + k0 + skc, &Al[buf][ii * 16][0]);
    }
#pragma unroll
    for (int t = 0; t < BN / 64; ++t) {
      const int ii = wid + t * 4;
      gload16(Bb + (long)(ii * 16 + srow) * ldb + k0 + skc, &Bl[buf][ii * 16][0]);
    }
  };

  f32x4 acc[MF][NF] = {};
  const int nk = K / BK;
  const int ar = lane & 15, ls = lane >> 4;

  stage(0, 0);
  if (nk > 1) stage(1, BK);
  for (int kt = 0; kt < nk; ++kt) {
    if (kt == nk - 1) {
      asm volatile("s_waitcnt vmcnt(0)" ::: "memory");
    } else if constexpr (LPS == 4) {
      asm volatile("s_waitcnt vmcnt(4)" ::: "memory");
    } else if constexpr (LPS == 3) {
      asm volatile("s_waitcnt vmcnt(3)" ::: "memory");
    } else {
      asm volatile("s_waitcnt vmcnt(0)" ::: "memory");
    }
    __builtin_amdgcn_s_barrier();
    asm volatile("" ::: "memory");
    if (kt + 2 < nk) stage((kt + 2) % 3, (kt + 2) * BK);
    const int cur = kt % 3;
    f16x8 af[MF], bv[NF];
#pragma unroll
    for (int m = 0; m < MF; ++m) {
      const int R = wm * WM + m * 16 + ar;
      af[m] = *(const f16x8*)&Al[cur][R][(ls ^ ((R >> 1) & 3)) * 8];
    }
#pragma unroll
    for (int n = 0; n < NF; ++n) {
      const int R = wn * WN + n * 16 + ar;
      bv[n] = *(const f16x8*)&Bl[cur][R][(ls ^ ((R >> 1) & 3)) * 8];
    }
#pragma unroll
    for (int m = 0; m < MF; ++m)
#pragma unroll
      for (int n = 0; n < NF; ++n)
        acc[m][n] = __builtin_amdgcn_mfma_f32_16x16x32_f16(af[m], bv[n], acc[m][n], 0, 0, 0);
  }

  const long coff = (long)zb * sCb + (long)zh * sCh;
#pragma unroll
  for (int m = 0; m < MF; ++m) {
#pragma unroll
    for (int n = 0; n < NF; ++n) {
      const int col = blockIdx.y * BN + wn * WN + n * 16 + ar;
      float bv1 = 0.f, bv2 = 0.f;
      if (FLAGS & F_BIAS) bv1 = bias[col];
      if (FLAGS & F_DUAL) bv2 = bias2[col];
#pragma unroll
      for (int r = 0; r < 4; ++r) {
        const int row = blockIdx.x * BM + wm * WM + m * 16 + (lane >> 4) * 4 + r;
        float val = acc[m][n][r] + bv1;
        if (FLAGS & F_RELU) val = fmaxf(val, 0.f);
        if constexpr ((FLAGS & F_ACC) != 0) {
          float* p = (float*)Cv + coff + (long)row * ldc + col;
          *p = *p + val;
        } else if constexpr ((FLAGS & F_OBF) != 0) {
          ((h16*)Cv)[coff + (long)row * ldc + col] = (h16)val;
          if constexpr ((FLAGS & F_DUAL) != 0)
            ((h16*)C2v)[coff + (long)row * ldc + col] = (h16)(acc[m][n][r] + bv2);
        } else {
          ((float*)Cv)[coff + (long)row * ldc + col] = val;
        }
      }
    }
  }
}

// ---------------------------------------------------------------------------
// Fused Transformer-XL attention (r6 version, unchanged).
// ---------------------------------------------------------------------------
__global__ __launch_bounds__(256) void fattn_k(
    const h16* __restrict__ qu, const h16* __restrict__ qv,
    const h16* __restrict__ kvb, const h16* __restrict__ vT,
    const h16* __restrict__ rb, h16* __restrict__ attn) {
  __shared__ h16 Kl[128][64];
  __shared__ h16 Vl[64][128];
  __shared__ h16 Psc[4][16][164];

  const int tid = threadIdx.x, lane = tid & 63, wv = tid >> 6;
  const int z = blockIdx.x, b = z >> 4, h = z & 15;
  const int i0 = blockIdx.y * 64;
  const int ar = lane & 15, q4 = lane >> 4;
  const int myrow = i0 + wv * 16;

  const long qoff = ((long)(myrow + ar) * 16 + b) * 1024 + h * 64 + q4 * 8;
  f16x8 quf[2], qvf[2];
  quf[0] = *(const f16x8*)&qu[qoff];
  quf[1] = *(const f16x8*)&qu[qoff + 32];
  qvf[0] = *(const f16x8*)&qv[qoff];
  qvf[1] = *(const f16x8*)&qv[qoff + 32];

  f32x4 o[4] = {};
  float mrow[4], lrow[4];
#pragma unroll
  for (int r = 0; r < 4; ++r) { mrow[r] = -3e38f; lrow[r] = 0.f; }

  const int ntiles = (i0 + 575 + 128) >> 7;

  for (int t = 0; t < ntiles; ++t) {
    const int j0 = t * 128;
    __builtin_amdgcn_s_barrier();
#pragma unroll
    for (int it = 0; it < 4; ++it) {
      const int ch = it * 256 + wv * 64 + lane;
      const int kr = ch >> 3, ks = ch & 7;
      gload16(kvb + ((long)(j0 + kr) * 16 + b) * 2048 + h * 64 + (ks ^ (kr & 7)) * 8,
              (char*)&Kl[0][0] + (it * 256 + wv * 64) * 16);
    }
#pragma unroll
    for (int it = 0; it < 4; ++it) {
      const int ch = it * 256 + wv * 64 + lane;
      const int vd = ch >> 4, vs = ch & 15;
      gload16(vT + ((long)z * 64 + vd) * 1024 + j0 + (vs ^ (vd & 7)) * 8,
              (char*)&Vl[0][0] + (it * 256 + wv * 64) * 16);
    }
    asm volatile("s_waitcnt vmcnt(0)" ::: "memory");
    __builtin_amdgcn_s_barrier();

    f32x4 acc_c[8] = {};
#pragma unroll
    for (int kd = 0; kd < 2; ++kd)
#pragma unroll
      for (int nf = 0; nf < 8; ++nf) {
        const int j = nf * 16 + ar;
        const int phys = (kd * 4 + q4) ^ (j & 7);
        const f16x8 kf = *(const f16x8*)&Kl[j][phys * 8];
        acc_c[nf] = __builtin_amdgcn_mfma_f32_16x16x32_f16(quf[kd], kf, acc_c[nf], 0, 0, 0);
      }

    const int jbase = j0 - myrow + 496;
    f32x4 acc_p[9] = {};
#pragma unroll
    for (int kd = 0; kd < 2; ++kd)
#pragma unroll
      for (int jf = 0; jf < 9; ++jf) {
        int jjr = jbase + jf * 16 + ar;
        if (jjr > 1023) jjr = 1023;
        const f16x8 rf = *(const f16x8*)&rb[(long)jjr * 1024 + h * 64 + kd * 32 + q4 * 8];
        acc_p[jf] = __builtin_amdgcn_mfma_f32_16x16x32_f16(qvf[kd], rf, acc_p[jf], 0, 0, 0);
      }
#pragma unroll
    for (int jf = 0; jf < 9; ++jf)
#pragma unroll
      for (int r = 0; r < 4; ++r)
        Psc[wv][q4 * 4 + r][jf * 16 + ar] = (h16)acc_p[jf][r];

    float p[8][4];
#pragma unroll
    for (int nf = 0; nf < 8; ++nf)
#pragma unroll
      for (int r = 0; r < 4; ++r) {
        const int iloc = q4 * 4 + r;
        const int jloc = nf * 16 + ar;
        const int band = jloc - iloc + 15;
        const float pv = (float)Psc[wv][iloc][band];
        float sv = (acc_c[nf][r] + pv) * 0.125f;
        const bool ok = (j0 + jloc) <= (myrow + iloc + 512);
        p[nf][r] = ok ? sv : -3e38f;
      }
#pragma unroll
    for (int r = 0; r < 4; ++r) {
      float tm = -3e38f;
#pragma unroll
      for (int nf = 0; nf < 8; ++nf) tm = fmaxf(tm, p[nf][r]);
      tm = fmaxf(tm, __shfl_xor(tm, 1));
      tm = fmaxf(tm, __shfl_xor(tm, 2));
      tm = fmaxf(tm, __shfl_xor(tm, 4));
      tm = fmaxf(tm, __shfl_xor(tm, 8));
      const float mn = fmaxf(mrow[r], tm);
      const float sc = __expf(mrow[r] - mn);
      mrow[r] = mn;
      float ts = 0.f;
#pragma unroll
      for (int nf = 0; nf < 8; ++nf) {
        const float e = __expf(p[nf][r] - mn);
        p[nf][r] = e;
        ts += e;
      }
      ts += __shfl_xor(ts, 1);
      ts += __shfl_xor(ts, 2);
      ts += __shfl_xor(ts, 4);
      ts += __shfl_xor(ts, 8);
      lrow[r] = lrow[r] * sc + ts;
#pragma unroll
      for (int v = 0; v < 4; ++v) o[v][r] *= sc;
    }

#pragma unroll
    for (int nf = 0; nf < 8; ++nf)
#pragma unroll
      for (int r = 0; r < 4; ++r) {
        const int iloc = q4 * 4 + r, jloc = nf * 16 + ar;
        Psc[wv][iloc][((jloc >> 3) ^ (iloc & 7)) * 8 + (jloc & 7)] = (h16)p[nf][r];
      }
#pragma unroll
    for (int ks = 0; ks < 4; ++ks) {
      const f16x8 pa = *(const f16x8*)&Psc[wv][ar][((ks * 4 + q4) ^ (ar & 7)) * 8];
#pragma unroll
      for (int vnf = 0; vnf < 4; ++vnf) {
        const int d = vnf * 16 + ar;
        const f16x8 vb = *(const f16x8*)&Vl[d][((ks * 4 + q4) ^ (d & 7)) * 8];
        o[vnf] = __builtin_amdgcn_mfma_f32_16x16x32_f16(pa, vb, o[vnf], 0, 0, 0);
      }
    }
  }

#pragma unroll
  for (int vnf = 0; vnf < 4; ++vnf)
#pragma unroll
    for (int r = 0; r < 4; ++r) {
      const int i_ = myrow + q4 * 4 + r;
      attn[((long)i_ * 16 + b) * 1024 + h * 64 + vnf * 16 + ar] =
          (h16)(o[vnf][r] / lrow[r]);
    }
}

// ---------------------------------------------------------------------------
__global__ __launch_bounds__(256) void wtrans_k(const float* __restrict__ in,
                                                h16* __restrict__ out, int K, int N) {
  __shared__ float t[32][33];
  const int tx = threadIdx.x & 31, ty = threadIdx.x >> 5;
  const int n0 = blockIdx.x * 32, k0 = blockIdx.y * 32;
#pragma unroll
  for (int j = 0; j < 32; j += 8)
    t[ty + j][tx] = in[(long)(k0 + ty + j) * N + n0 + tx];
  __syncthreads();
#pragma unroll
  for (int j = 0; j < 32; j += 8)
    out[(long)(n0 + ty + j) * K + k0 + tx] = (h16)t[tx][ty + j];
}

__global__ __launch_bounds__(256) void cast_k(const float* __restrict__ in,
                                              h16* __restrict__ out, long n4) {
  const long i = (long)blockIdx.x * 256 + threadIdx.x;
  if (i >= n4) return;
  const float4 v = ((const float4*)in)[i];
  f16x4 o;
  o[0] = (h16)v.x; o[1] = (h16)v.y; o[2] = (h16)v.z; o[3] = (h16)v.w;
  ((f16x4*)out)[i] = o;
}

__global__ void addbias_k(const float* __restrict__ bq, const float* __restrict__ u,
                          const float* __restrict__ v, float* __restrict__ qu,
                          float* __restrict__ qv) {
  const int c = blockIdx.x * 256 + threadIdx.x;
  if (c < 1024) { qu[c] = bq[c] + u[c]; qv[c] = bq[c] + v[c]; }
}

__global__ __launch_bounds__(256) void zero_out_k(float* __restrict__ out, long n) {
  const long i = (long)blockIdx.x * 256 + threadIdx.x;
  if (i < n) out[i] = 0.f;
}

__global__ __launch_bounds__(256) void ln_k(const float* __restrict__ src0,
                                            const float* __restrict__ src1, int rows0,
                                            const float* __restrict__ g,
                                            const float* __restrict__ b,
                                            h16* __restrict__ out) {
  const int row = blockIdx.x, tid = threadIdx.x;
  const float* src = (row < rows0) ? (src0 + (long)row * 1024)
                                   : (src1 + (long)(row - rows0) * 1024);
  const float4 x = ((const float4*)src)[tid];
  float s = x.x + x.y + x.z + x.w;
  float sq = x.x * x.x + x.y * x.y + x.z * x.z + x.w * x.w;
#pragma unroll
  for (int o = 32; o > 0; o >>= 1) { s += __shfl_down(s, o); sq += __shfl_down(sq, o); }
  __shared__ float red[8];
  const int lane = tid & 63, w = tid >> 6;
  if (lane == 0) { red[w] = s; red[4 + w] = sq; }
  __syncthreads();
  s = red[0] + red[1] + red[2] + red[3];
  sq = red[4] + red[5] + red[6] + red[7];
  const float mu = s * (1.f / 1024.f);
  const float inv = rsqrtf(sq * (1.f / 1024.f) - mu * mu + 1e-5f);
  const float4 gg = ((const float4*)g)[tid], bb = ((const float4*)b)[tid];
  f16x4 o;
  o[0] = (h16)((x.x - mu) * inv * gg.x + bb.x);
  o[1] = (h16)((x.y - mu) * inv * gg.y + bb.y);
  o[2] = (h16)((x.z - mu) * inv * gg.z + bb.z);
  o[3] = (h16)((x.w - mu) * inv * gg.w + bb.w);
  ((f16x4*)(out + (long)row * 1024))[tid] = o;
}

__global__ __launch_bounds__(256) void vtrans_k(const h16* __restrict__ kv,
                                                h16* __restrict__ vT) {
  const int z = blockIdx.y, b = z >> 4, h = z & 15;
  const int j0 = blockIdx.x * 64;
  __shared__ h16 t[64][72];
  const int jj = threadIdx.x >> 3, c = threadIdx.x & 7;
#pragma unroll
  for (int half = 0; half < 2; ++half) {
    const int j = jj + half * 32;
    const f16x8 v = *(const f16x8*)(kv + ((long)(j0 + j) * 16 + b) * 2048 + 1024 + h * 64 + c * 8);
    *(f16x8*)&t[j][c * 8] = v;
  }
  __syncthreads();
#pragma unroll
  for (int half = 0; half < 2; ++half) {
    const int d = jj + half * 32;
    f16x8 o;
#pragma unroll
    for (int k = 0; k < 8; ++k) o[k] = t[c * 8 + k][d];
    *(f16x8*)(vT + ((long)z * 64 + d) * 1024 + j0 + c * 8) = o;
  }
}

__global__ __launch_bounds__(256) void gru_rx_k(const float* __restrict__ T,
                                                const float* __restrict__ x,
                                                h16* __restrict__ rx) {
  const long i = (long)blockIdx.x * 256 + threadIdx.x;
  const long row = i >> 8;
  const int c4 = (int)(i & 255);
  const float4 t = *((const float4*)(T + row * 3072) + c4);
  const float4 xx = ((const float4*)x)[i];
  f16x4 o;
  o[0] = (h16)(xx.x / (1.f + __expf(-t.x)));
  o[1] = (h16)(xx.y / (1.f + __expf(-t.y)));
  o[2] = (h16)(xx.z / (1.f + __expf(-t.z)));
  o[3] = (h16)(xx.w / (1.f + __expf(-t.w)));
  ((f16x4*)rx)[i] = o;
}

__global__ __launch_bounds__(256) void gru_out_k(const float* __restrict__ T,
                                                 const float* __restrict__ x,
                                                 const float* __restrict__ bg,
                                                 float* __restrict__ outf,
                                                 h16* __restrict__ outh) {
  const long i = (long)blockIdx.x * 256 + threadIdx.x;
  const long row = i >> 8;
  const int c4 = (int)(i & 255);
  const float4 tz = *((const float4*)(T + row * 3072 + 1024) + c4);
  const float4 th = *((const float4*)(T + row * 3072 + 2048) + c4);
  const float4 xx = ((const float4*)x)[i];
  const float4 bb = ((const float4*)bg)[c4];
  float4 o;
  {
    const float z0 = 1.f / (1.f + __expf(-(tz.x - bb.x)));
    const float z1 = 1.f / (1.f + __expf(-(tz.y - bb.y)));
    const float z2 = 1.f / (1.f + __expf(-(tz.z - bb.z)));
    const float z3 = 1.f / (1.f + __expf(-(tz.w - bb.w)));
    o.x = (1.f - z0) * xx.x + z0 * tanhf(th.x);
    o.y = (1.f - z1) * xx.y + z1 * tanhf(th.y);
    o.z = (1.f - z2) * xx.z + z2 * tanhf(th.z);
    o.w = (1.f - z3) * xx.w + z3 * tanhf(th.w);
  }
  ((float4*)outf)[i] = o;
  if (outh != nullptr) {
    f16x4 oh;
    oh[0] = (h16)o.x; oh[1] = (h16)o.y; oh[2] = (h16)o.z; oh[3] = (h16)o.w;
    ((f16x4*)outh)[i] = oh;
  }
}

// ---------------------------------------------------------------------------
extern "C" void kernel_launch(void* const* d_in, const int* in_sizes, int n_in,
                              void* d_out, int out_size, void* d_ws, size_t ws_size,
                              hipStream_t stream) {
  const float* inputs = (const float*)d_in[0];
  const float* pos    = (const float*)d_in[1];
  const float* u      = (const float*)d_in[2];
  const float* v      = (const float*)d_in[3];
  const float* memory = (const float*)d_in[4];
  const float* Wkv = (const float*)d_in[6];  const float* bkv = (const float*)d_in[7];
  const float* Wq  = (const float*)d_in[8];  const float* bq  = (const float*)d_in[9];
  const float* Wo  = (const float*)d_in[10]; const float* bo  = (const float*)d_in[11];
  const float* Wp  = (const float*)d_in[12]; const float* bp  = (const float*)d_in[13];
  const float* ln1_g = (const float*)d_in[14]; const float* ln1_b = (const float*)d_in[15];
  const float* ln2_g = (const float*)d_in[16]; const float* ln2_b = (const float*)d_in[17];
  const float* W1 = (const float*)d_in[18]; const float* b1 = (const float*)d_in[19];
  const float* W2 = (const float*)d_in[20]; const float* b2 = (const float*)d_in[21];
  const float* g1_W = (const float*)d_in[22]; const float* g1_U = (const float*)d_in[23];
  const float* g1_bg = (const float*)d_in[24];
  const float* g2_W = (const float*)d_in[25]; const float* g2_U = (const float*)d_in[26];
  const float* g2_bg = (const float*)d_in[27];
  (void)in_sizes; (void)n_in;

  const size_t MB = 1u << 20;
  const size_t NEEDED = 247 * MB;
  const dim3 blk(256);
  if (ws_size < NEEDED) {
    zero_out_k<<<(out_size + 255) / 256, blk, 0, stream>>>((float*)d_out, out_size);
    return;
  }

  char* w = (char*)d_ws;
  h16* WoT   = (h16*)(w + 0 * MB);
  h16* W1T   = (h16*)(w + 2 * MB);
  h16* W2T   = (h16*)(w + 10 * MB);
  h16* g1Wb  = (h16*)(w + 18 * MB);
  h16* g1Ub  = (h16*)(w + 24 * MB);
  h16* g2Wb  = (h16*)(w + 30 * MB);
  h16* g2Ub  = (h16*)(w + 36 * MB);
  h16* WkvT  = (h16*)(w + 42 * MB);
  h16* WqT   = (h16*)(w + 46 * MB);
  h16* WpT   = (h16*)(w + 48 * MB);
  h16* posb  = (h16*)(w + 50 * MB);
  float* bias_qu = (float*)(w + 52 * MB);
  float* bias_qv = (float*)(w + 52 * MB + 8192);
  h16* xb    = (h16*)(w + 53 * MB);
  h16* x1    = (h16*)(w + 69 * MB);
  char* Rbig =        w + 101 * MB;
  h16* qu    = (h16*)(w + 197 * MB);
  h16* qv    = (h16*)(w + 213 * MB);
  h16* rb    = (h16*)(w + 229 * MB);
  h16* attn  = (h16*)(w + 231 * MB);

  h16*   kvb  = (h16*)Rbig;
  float* Tall = (float*)Rbig;
  h16*   h1   = (h16*)Rbig;
  h16*   vT   = x1;
  h16*   a1   = qu;
  h16*   rx1  = qv;
  float* o1f  = (float*)qu;
  h16*   o1b  = attn;
  h16*   x2   = x1;
  h16*   m2   = x1 + 8L * 1024 * 1024;
  h16*   rx2  = x1;

  // ---- weight prep ----
  wtrans_k<<<dim3(64, 32), blk, 0, stream>>>(Wkv, WkvT, 1024, 2048);
  wtrans_k<<<dim3(32, 32), blk, 0, stream>>>(Wq, WqT, 1024, 1024);
  wtrans_k<<<dim3(32, 32), blk, 0, stream>>>(Wo, WoT, 1024, 1024);
  wtrans_k<<<dim3(32, 32), blk, 0, stream>>>(Wp, WpT, 1024, 1024);
  wtrans_k<<<dim3(128, 32), blk, 0, stream>>>(W1, W1T, 1024, 4096);
  wtrans_k<<<dim3(32, 128), blk, 0, stream>>>(W2, W2T, 4096, 1024);
  cast_k<<<3072, blk, 0, stream>>>(g1_W, g1Wb, 786432);
  cast_k<<<3072, blk, 0, stream>>>(g1_U, g1Ub, 786432);
  cast_k<<<3072, blk, 0, stream>>>(g2_W, g2Wb, 786432);
  cast_k<<<3072, blk, 0, stream>>>(g2_U, g2Ub, 786432);
  cast_k<<<1024, blk, 0, stream>>>(pos, posb, 262144);
  cast_k<<<8192, blk, 0, stream>>>(inputs, xb, 2097152);
  addbias_k<<<4, blk, 0, stream>>>(bq, u, v, bias_qu, bias_qv);

  // ---- ln1 ----
  ln_k<<<16384, blk, 0, stream>>>(memory, inputs, 8192, ln1_g, ln1_b, x1);

  // ---- projections ----
  gemm2_k<F_OBF | F_BIAS><<<dim3(512), dim3(512), 0, stream>>>(
      x1, WkvT, kvb, bkv, 1024, 1024, 1024, 2048, 64);
  gemm_k<64, 128, 2, 2, F_OBF | F_BIAS | F_DUAL><<<dim3(128, 8, 1), blk, 0, stream>>>(
      x1 + 8192L * 1024, WqT, qu, qv, bias_qu, bias_qv, 1024, 1024, 1024, 1024, 0, 0, 0, 0, 0, 0);
  gemm_k<128, 128, 2, 2, F_OBF | F_BIAS><<<dim3(8, 8, 1), blk, 0, stream>>>(
      posb, WpT, rb, nullptr, bp, nullptr, 1024, 1024, 1024, 1024, 0, 0, 0, 0, 0, 0);
  vtrans_k<<<dim3(16, 256), blk, 0, stream>>>(kvb, vT);

  // ---- fused attention ----
  fattn_k<<<dim3(256, 8), blk, 0, stream>>>(qu, qv, kvb, vT, rb, attn);

  // ---- output projection + relu -> a1 ----
  gemm_k<64, 128, 2, 2, F_OBF | F_BIAS | F_RELU><<<dim3(128, 8, 1), blk, 0, stream>>>(
      attn, WoT, a1, nullptr, bo, nullptr, 1024, 1024, 1024, 1024, 0, 0, 0, 0, 0, 0);

  // ---- GRU gate 1 ----
  gemm2_k<0><<<dim3(384), dim3(512), 0, stream>>>(
      a1, g1Wb, Tall, nullptr, 1024, 1024, 1024, 3072, 32);
  gemm2_k<F_ACC><<<dim3(256), dim3(512), 0, stream>>>(
      xb, g1Ub, Tall, nullptr, 1024, 1024, 1024, 3072, 32);
  gru_rx_k<<<8192, blk, 0, stream>>>(Tall, inputs, rx1);
  gemm_k<64, 128, 2, 2, F_ACC><<<dim3(128, 8, 1), blk, 0, stream>>>(
      rx1, g1Ub + 2L * 1024 * 1024, Tall + 2048, nullptr, nullptr, nullptr,
      1024, 1024, 1024, 3072, 0, 0, 0, 0, 0, 0);
  gru_out_k<<<8192, blk, 0, stream>>>(Tall, inputs, g1_bg, o1f, o1b);

  // ---- ln2 + MLP ----
  ln_k<<<8192, blk, 0, stream>>>(o1f, o1f, 8192, ln2_g, ln2_b, x2);
  gemm2_k<F_OBF | F_BIAS | F_RELU><<<dim3(512), dim3(512), 0, stream>>>(
      x2, W1T, h1, b1, 1024, 1024, 1024, 4096, 32);
  gemm_k<64, 128, 2, 2, F_OBF | F_BIAS | F_RELU><<<dim3(128, 8, 1), blk, 0, stream>>>(
      h1, W2T, m2, nullptr, b2, nullptr, 4096, 4096, 4096, 1024, 0, 0, 0, 0, 0, 0);

  // ---- GRU gate 2 ----
  gemm2_k<0><<<dim3(384), dim3(512), 0, stream>>>(
      m2, g2Wb, Tall, nullptr, 1024, 1024, 1024, 3072, 32);
  gemm2_k<F_ACC><<<dim3(256), dim3(512), 0, stream>>>(
      o1b, g2Ub, Tall, nullptr, 1024, 1024, 1024, 3072, 32);
  gru_rx_k<<<8192, blk, 0, stream>>>(Tall, o1f, rx2);
  gemm_k<64, 128, 2, 2, F_ACC><<<dim3(128, 8, 1), blk, 0, stream>>>(
      rx2, g2Ub + 2L * 1024 * 1024, Tall + 2048, nullptr, nullptr, nullptr,
      1024, 1024, 1024, 3072, 0, 0, 0, 0, 0, 0);
  gru_out_k<<<8192, blk, 0, stream>>>(Tall, o1f, g2_bg, (float*)d_out, nullptr);
}